// Round 1
// baseline (1916.559 us; speedup 1.0000x reference)
//
#include <hip/hip_runtime.h>
#include <math.h>

#define NN 50000
#define NE 800000
#define D  256
#define BM 128
#define BN 128
#define BK 16

// ---------------- degree / inverse count ----------------
__global__ void degree_kernel(const int* __restrict__ dst, float* __restrict__ cnt) {
    int e = blockIdx.x * blockDim.x + threadIdx.x;
    if (e < NE) atomicAdd(&cnt[dst[e]], 1.0f);
}

__global__ void invcnt_kernel(float* __restrict__ cnt) {
    int i = blockIdx.x * blockDim.x + threadIdx.x;
    if (i < NN) {
        float c = cnt[i];
        cnt[i] = (c > 0.0f) ? 1.0f / c : 0.0f;
    }
}

// ---------------- scatter-add of rows: s[dst] += rows[src] ----------------
// grid = NE blocks, block = 256 threads (one edge per block, thread j = column j)
__global__ void scatter_kernel(const float* __restrict__ rows,
                               const int* __restrict__ src,
                               const int* __restrict__ dst,
                               float* __restrict__ s) {
    int e = blockIdx.x;
    int j = threadIdx.x;
    int sn = src[e];
    int dn = dst[e];
    atomicAdd(&s[(size_t)dn * D + j], rows[(size_t)sn * D + j]);
}

// ---------------- fused SAGE GEMM: C = (s*inv) @ Wl^T + xr @ Wr^T + bias ----
// M = NN, N = 256, K = 512 (first 256 from s*inv, next 256 from xr)
__global__ __launch_bounds__(256)
void sage_gemm_kernel(const float* __restrict__ s,
                      const float* __restrict__ inv,
                      const float* __restrict__ xr,
                      const float* __restrict__ Wl,
                      const float* __restrict__ Wr,
                      const float* __restrict__ bias,
                      float* __restrict__ C) {
    __shared__ float As[BK][BM + 4];
    __shared__ float Bs[BK][BN + 4];
    const int tid = threadIdx.x;
    const int tx = tid & 15;        // 0..15 -> 8 cols each
    const int ty = tid >> 4;        // 0..15 -> 8 rows each
    const int row0 = blockIdx.x * BM;
    const int col0 = blockIdx.y * BN;
    const int lr = tid >> 2;        // 0..63
    const int lc = (tid & 3) * 4;   // 0,4,8,12

    float acc[8][8];
#pragma unroll
    for (int i = 0; i < 8; i++)
#pragma unroll
        for (int j = 0; j < 8; j++) acc[i][j] = 0.0f;

    for (int k0 = 0; k0 < 2 * D; k0 += BK) {
        const int kk0 = k0 & (D - 1);
        const int r0 = row0 + lr;
        const int r1 = row0 + lr + 64;
        float4 a0 = make_float4(0.f, 0.f, 0.f, 0.f);
        float4 a1 = make_float4(0.f, 0.f, 0.f, 0.f);
        if (k0 < D) {
            if (r0 < NN) {
                a0 = *(const float4*)&s[(size_t)r0 * D + kk0 + lc];
                float i0 = inv[r0];
                a0.x *= i0; a0.y *= i0; a0.z *= i0; a0.w *= i0;
            }
            if (r1 < NN) {
                a1 = *(const float4*)&s[(size_t)r1 * D + kk0 + lc];
                float i1 = inv[r1];
                a1.x *= i1; a1.y *= i1; a1.z *= i1; a1.w *= i1;
            }
        } else {
            if (r0 < NN) a0 = *(const float4*)&xr[(size_t)r0 * D + kk0 + lc];
            if (r1 < NN) a1 = *(const float4*)&xr[(size_t)r1 * D + kk0 + lc];
        }
        const float* __restrict__ W = (k0 < D) ? Wl : Wr;
        float4 b0 = *(const float4*)&W[(size_t)(col0 + lr) * D + kk0 + lc];
        float4 b1 = *(const float4*)&W[(size_t)(col0 + lr + 64) * D + kk0 + lc];

        __syncthreads();
        As[lc + 0][lr] = a0.x; As[lc + 1][lr] = a0.y; As[lc + 2][lr] = a0.z; As[lc + 3][lr] = a0.w;
        As[lc + 0][lr + 64] = a1.x; As[lc + 1][lr + 64] = a1.y; As[lc + 2][lr + 64] = a1.z; As[lc + 3][lr + 64] = a1.w;
        Bs[lc + 0][lr] = b0.x; Bs[lc + 1][lr] = b0.y; Bs[lc + 2][lr] = b0.z; Bs[lc + 3][lr] = b0.w;
        Bs[lc + 0][lr + 64] = b1.x; Bs[lc + 1][lr + 64] = b1.y; Bs[lc + 2][lr + 64] = b1.z; Bs[lc + 3][lr + 64] = b1.w;
        __syncthreads();

#pragma unroll
        for (int kk = 0; kk < BK; kk++) {
            float a[8], b[8];
            *(float4*)&a[0] = *(const float4*)&As[kk][ty * 8 + 0];
            *(float4*)&a[4] = *(const float4*)&As[kk][ty * 8 + 4];
            *(float4*)&b[0] = *(const float4*)&Bs[kk][tx * 8 + 0];
            *(float4*)&b[4] = *(const float4*)&Bs[kk][tx * 8 + 4];
#pragma unroll
            for (int i = 0; i < 8; i++)
#pragma unroll
                for (int j = 0; j < 8; j++)
                    acc[i][j] = fmaf(a[i], b[j], acc[i][j]);
        }
    }

#pragma unroll
    for (int i = 0; i < 8; i++) {
        int r = row0 + ty * 8 + i;
        if (r < NN) {
#pragma unroll
            for (int j = 0; j < 8; j += 4) {
                int c = col0 + tx * 8 + j;
                float4 v;
                v.x = acc[i][j + 0] + bias[c + 0];
                v.y = acc[i][j + 1] + bias[c + 1];
                v.z = acc[i][j + 2] + bias[c + 2];
                v.w = acc[i][j + 3] + bias[c + 3];
                *(float4*)&C[(size_t)r * D + c] = v;
            }
        }
    }
}

// ---------------- per-column sum & sumsq for BN ----------------
__global__ void colstats_kernel(const float* __restrict__ h, float* __restrict__ stats) {
    int j = threadIdx.x;
    float s0 = 0.f, s1 = 0.f;
    for (int r = blockIdx.x; r < NN; r += gridDim.x) {
        float v = h[(size_t)r * D + j];
        s0 += v;
        s1 += v * v;
    }
    atomicAdd(&stats[j], s0);
    atomicAdd(&stats[D + j], s1);
}

__global__ void bnfin_kernel(const float* __restrict__ stats,
                             const float* __restrict__ gamma,
                             const float* __restrict__ beta,
                             float* __restrict__ scale,
                             float* __restrict__ shift) {
    int j = threadIdx.x;
    const float invN = 1.0f / (float)NN;
    float mu = stats[j] * invN;
    float var = stats[D + j] * invN - mu * mu;
    float sc = gamma[j] * rsqrtf(var + 1e-5f);
    scale[j] = sc;
    shift[j] = beta[j] - mu * sc;
}

// ---------------- BN + ReLU in place (float4) ----------------
__global__ void bnrelu_kernel(float* __restrict__ h,
                              const float* __restrict__ scale,
                              const float* __restrict__ shift) {
    size_t idx = (size_t)blockIdx.x * blockDim.x + threadIdx.x;  // float4 index
    int j0 = ((int)idx & 63) * 4;
    float4 v = ((float4*)h)[idx];
    float4 sc = *(const float4*)&scale[j0];
    float4 sh = *(const float4*)&shift[j0];
    v.x = fmaxf(v.x * sc.x + sh.x, 0.f);
    v.y = fmaxf(v.y * sc.y + sh.y, 0.f);
    v.z = fmaxf(v.z * sc.z + sh.z, 0.f);
    v.w = fmaxf(v.w * sc.w + sh.w, 0.f);
    ((float4*)h)[idx] = v;
}

// ---------------- row L2 normalize (one wave per row) ----------------
__global__ void l2norm_kernel(float* __restrict__ out) {
    int wave = threadIdx.x >> 6;  // 0..3
    int lane = threadIdx.x & 63;
    for (int r = blockIdx.x * 4 + wave; r < NN; r += gridDim.x * 4) {
        float4 v = *(float4*)&out[(size_t)r * D + lane * 4];
        float sq = v.x * v.x + v.y * v.y + v.z * v.z + v.w * v.w;
#pragma unroll
        for (int o = 32; o; o >>= 1) sq += __shfl_xor(sq, o);
        float invn = 1.0f / fmaxf(sqrtf(sq), 1e-12f);
        v.x *= invn; v.y *= invn; v.z *= invn; v.w *= invn;
        *(float4*)&out[(size_t)r * D + lane * 4] = v;
    }
}

// ---------------- column sum of node_emb for pooling ----------------
__global__ void colsum_kernel(const float* __restrict__ h, float* __restrict__ gsum) {
    int j = threadIdx.x;
    float s0 = 0.f;
    for (int r = blockIdx.x; r < NN; r += gridDim.x) s0 += h[(size_t)r * D + j];
    atomicAdd(&gsum[j], s0);
}

// ---------------- final graph embedding ----------------
__global__ void graph_kernel(const float* __restrict__ gsum, float* __restrict__ gout) {
    __shared__ float wsum[4];
    int j = threadIdx.x;
    float v = gsum[j] * (1.0f / (float)NN);
    float sq = v * v;
#pragma unroll
    for (int o = 32; o; o >>= 1) sq += __shfl_xor(sq, o);
    if ((j & 63) == 0) wsum[j >> 6] = sq;
    __syncthreads();
    float tot = wsum[0] + wsum[1] + wsum[2] + wsum[3];
    gout[j] = v / fmaxf(sqrtf(tot), 1e-12f);
}

extern "C" void kernel_launch(void* const* d_in, const int* in_sizes, int n_in,
                              void* d_out, int out_size, void* d_ws, size_t ws_size,
                              hipStream_t stream) {
    const float* x      = (const float*)d_in[0];
    const float* W1_l   = (const float*)d_in[1];
    const float* b1_l   = (const float*)d_in[2];
    const float* W1_r   = (const float*)d_in[3];
    const float* W2_l   = (const float*)d_in[4];
    const float* b2_l   = (const float*)d_in[5];
    const float* W2_r   = (const float*)d_in[6];
    const float* gamma1 = (const float*)d_in[7];
    const float* beta1  = (const float*)d_in[8];
    const int*   eidx   = (const int*)d_in[9];
    const int* src = eidx;
    const int* dst = eidx + NE;

    float* ws    = (float*)d_ws;
    float* cnt   = ws;              // [NN]
    float* stats = ws + 50048;      // [512]
    float* gsum  = ws + 50560;      // [256]
    float* scale = ws + 50816;      // [256]
    float* shift = ws + 51072;      // [256]
    float* s     = ws + 51328;      // [NN*D]
    float* h1    = s + (size_t)NN * D;  // [NN*D]
    float* out   = (float*)d_out;
    float* gout  = out + (size_t)NN * D;

    hipMemsetAsync(d_ws, 0, 51328 * sizeof(float), stream);
    hipMemsetAsync(s, 0, (size_t)NN * D * sizeof(float), stream);

    degree_kernel<<<(NE + 255) / 256, 256, 0, stream>>>(dst, cnt);
    invcnt_kernel<<<(NN + 255) / 256, 256, 0, stream>>>(cnt);

    // layer 1
    scatter_kernel<<<NE, D, 0, stream>>>(x, src, dst, s);
    dim3 ggrid((NN + BM - 1) / BM, D / BN);
    sage_gemm_kernel<<<ggrid, 256, 0, stream>>>(s, cnt, x, W1_l, W1_r, b1_l, h1);
    colstats_kernel<<<256, D, 0, stream>>>(h1, stats);
    bnfin_kernel<<<1, D, 0, stream>>>(stats, gamma1, beta1, scale, shift);
    bnrelu_kernel<<<12500, 256, 0, stream>>>(h1, scale, shift);

    // layer 2
    hipMemsetAsync(s, 0, (size_t)NN * D * sizeof(float), stream);
    scatter_kernel<<<NE, D, 0, stream>>>(h1, src, dst, s);
    sage_gemm_kernel<<<ggrid, 256, 0, stream>>>(s, cnt, h1, W2_l, W2_r, b2_l, out);

    // outputs
    l2norm_kernel<<<2048, 256, 0, stream>>>(out);
    colsum_kernel<<<256, D, 0, stream>>>(out, gsum);
    graph_kernel<<<1, D, 0, stream>>>(gsum, gout);
}

// Round 2
// 924.185 us; speedup vs baseline: 2.0738x; 2.0738x over previous
//
#include <hip/hip_runtime.h>
#include <math.h>

#define NN 50000
#define NE 800000
#define D  256
#define BM 128
#define BN 128
#define BK 16

// ---------------- CSR build: degree ----------------
__global__ void degree_kernel(const int* __restrict__ dst, int* __restrict__ deg) {
    int e = blockIdx.x * blockDim.x + threadIdx.x;
    if (e < NE) atomicAdd(&deg[dst[e]], 1);
}

// ---------------- single-block scan: offs = exclusive_scan(deg) ----------------
__global__ __launch_bounds__(1024)
void scan_kernel(const int* __restrict__ deg, int* __restrict__ offs) {
    __shared__ int sm[1024];
    const int t = threadIdx.x;
    const int C = (NN + 1023) / 1024;  // 49
    const int start = t * C;
    const int end = min(start + C, NN);
    int local = 0;
    for (int i = start; i < end; i++) local += deg[i];
    sm[t] = local;
    __syncthreads();
    for (int off = 1; off < 1024; off <<= 1) {
        int v = 0;
        if (t >= off) v = sm[t - off];
        __syncthreads();
        sm[t] += v;
        __syncthreads();
    }
    int run = (t > 0) ? sm[t - 1] : 0;  // exclusive base
    for (int i = start; i < end; i++) {
        offs[i] = run;
        run += deg[i];
    }
    if (t == 1023) offs[NN] = sm[1023];
}

__global__ void cursor_kernel(const int* __restrict__ offs, int* __restrict__ cur) {
    int i = blockIdx.x * blockDim.x + threadIdx.x;
    if (i < NN) cur[i] = offs[i];
}

__global__ void fill_kernel(const int* __restrict__ src, const int* __restrict__ dst,
                            int* __restrict__ cur, int* __restrict__ csr) {
    int e = blockIdx.x * blockDim.x + threadIdx.x;
    if (e < NE) {
        int pos = atomicAdd(&cur[dst[e]], 1);
        csr[pos] = src[e];
    }
}

// ---------------- mean aggregation: one wave per node ----------------
__global__ __launch_bounds__(256)
void agg_kernel(const float* __restrict__ rows, const int* __restrict__ csr,
                const int* __restrict__ offs, float* __restrict__ s) {
    int wid = (blockIdx.x * blockDim.x + threadIdx.x) >> 6;
    int lane = threadIdx.x & 63;
    if (wid >= NN) return;
    int beg = offs[wid];
    int end = offs[wid + 1];
    float4 acc = make_float4(0.f, 0.f, 0.f, 0.f);
    int e = beg;
    for (; e + 1 < end; e += 2) {
        int s0 = csr[e];
        int s1 = csr[e + 1];
        float4 v0 = *(const float4*)&rows[(size_t)s0 * D + lane * 4];
        float4 v1 = *(const float4*)&rows[(size_t)s1 * D + lane * 4];
        acc.x += v0.x; acc.y += v0.y; acc.z += v0.z; acc.w += v0.w;
        acc.x += v1.x; acc.y += v1.y; acc.z += v1.z; acc.w += v1.w;
    }
    if (e < end) {
        int s0 = csr[e];
        float4 v0 = *(const float4*)&rows[(size_t)s0 * D + lane * 4];
        acc.x += v0.x; acc.y += v0.y; acc.z += v0.z; acc.w += v0.w;
    }
    int c = end - beg;
    float sc = (c > 0) ? 1.0f / (float)c : 0.0f;
    acc.x *= sc; acc.y *= sc; acc.z *= sc; acc.w *= sc;
    *(float4*)&s[(size_t)wid * D + lane * 4] = acc;
}

// ---------------- fused SAGE GEMM: C = s @ Wl^T + xr @ Wr^T + bias ----
// M = NN, N = 256, K = 512 (first 256 from s (pre-averaged), next 256 from xr)
__global__ __launch_bounds__(256)
void sage_gemm_kernel(const float* __restrict__ s,
                      const float* __restrict__ xr,
                      const float* __restrict__ Wl,
                      const float* __restrict__ Wr,
                      const float* __restrict__ bias,
                      float* __restrict__ C) {
    __shared__ float As[BK][BM + 4];
    __shared__ float Bs[BK][BN + 4];
    const int tid = threadIdx.x;
    const int tx = tid & 15;        // 0..15 -> 8 cols each
    const int ty = tid >> 4;        // 0..15 -> 8 rows each
    const int row0 = blockIdx.x * BM;
    const int col0 = blockIdx.y * BN;
    const int lr = tid >> 2;        // 0..63
    const int lc = (tid & 3) * 4;   // 0,4,8,12

    float acc[8][8];
#pragma unroll
    for (int i = 0; i < 8; i++)
#pragma unroll
        for (int j = 0; j < 8; j++) acc[i][j] = 0.0f;

    for (int k0 = 0; k0 < 2 * D; k0 += BK) {
        const int kk0 = k0 & (D - 1);
        const int r0 = row0 + lr;
        const int r1 = row0 + lr + 64;
        const float* __restrict__ A = (k0 < D) ? s : xr;
        float4 a0 = make_float4(0.f, 0.f, 0.f, 0.f);
        float4 a1 = make_float4(0.f, 0.f, 0.f, 0.f);
        if (r0 < NN) a0 = *(const float4*)&A[(size_t)r0 * D + kk0 + lc];
        if (r1 < NN) a1 = *(const float4*)&A[(size_t)r1 * D + kk0 + lc];
        const float* __restrict__ W = (k0 < D) ? Wl : Wr;
        float4 b0 = *(const float4*)&W[(size_t)(col0 + lr) * D + kk0 + lc];
        float4 b1 = *(const float4*)&W[(size_t)(col0 + lr + 64) * D + kk0 + lc];

        __syncthreads();
        As[lc + 0][lr] = a0.x; As[lc + 1][lr] = a0.y; As[lc + 2][lr] = a0.z; As[lc + 3][lr] = a0.w;
        As[lc + 0][lr + 64] = a1.x; As[lc + 1][lr + 64] = a1.y; As[lc + 2][lr + 64] = a1.z; As[lc + 3][lr + 64] = a1.w;
        Bs[lc + 0][lr] = b0.x; Bs[lc + 1][lr] = b0.y; Bs[lc + 2][lr] = b0.z; Bs[lc + 3][lr] = b0.w;
        Bs[lc + 0][lr + 64] = b1.x; Bs[lc + 1][lr + 64] = b1.y; Bs[lc + 2][lr + 64] = b1.z; Bs[lc + 3][lr + 64] = b1.w;
        __syncthreads();

#pragma unroll
        for (int kk = 0; kk < BK; kk++) {
            float a[8], b[8];
            *(float4*)&a[0] = *(const float4*)&As[kk][ty * 8 + 0];
            *(float4*)&a[4] = *(const float4*)&As[kk][ty * 8 + 4];
            *(float4*)&b[0] = *(const float4*)&Bs[kk][tx * 8 + 0];
            *(float4*)&b[4] = *(const float4*)&Bs[kk][tx * 8 + 4];
#pragma unroll
            for (int i = 0; i < 8; i++)
#pragma unroll
                for (int j = 0; j < 8; j++)
                    acc[i][j] = fmaf(a[i], b[j], acc[i][j]);
        }
    }

#pragma unroll
    for (int i = 0; i < 8; i++) {
        int r = row0 + ty * 8 + i;
        if (r < NN) {
#pragma unroll
            for (int j = 0; j < 8; j += 4) {
                int c = col0 + tx * 8 + j;
                float4 v;
                v.x = acc[i][j + 0] + bias[c + 0];
                v.y = acc[i][j + 1] + bias[c + 1];
                v.z = acc[i][j + 2] + bias[c + 2];
                v.w = acc[i][j + 3] + bias[c + 3];
                *(float4*)&C[(size_t)r * D + c] = v;
            }
        }
    }
}

// ---------------- per-column sum & sumsq for BN ----------------
__global__ void colstats_kernel(const float* __restrict__ h, float* __restrict__ stats) {
    int j = threadIdx.x;
    float s0 = 0.f, s1 = 0.f;
    for (int r = blockIdx.x; r < NN; r += gridDim.x) {
        float v = h[(size_t)r * D + j];
        s0 += v;
        s1 += v * v;
    }
    atomicAdd(&stats[j], s0);
    atomicAdd(&stats[D + j], s1);
}

__global__ void bnfin_kernel(const float* __restrict__ stats,
                             const float* __restrict__ gamma,
                             const float* __restrict__ beta,
                             float* __restrict__ scale,
                             float* __restrict__ shift) {
    int j = threadIdx.x;
    const float invN = 1.0f / (float)NN;
    float mu = stats[j] * invN;
    float var = stats[D + j] * invN - mu * mu;
    float sc = gamma[j] * rsqrtf(var + 1e-5f);
    scale[j] = sc;
    shift[j] = beta[j] - mu * sc;
}

// ---------------- BN + ReLU in place (float4) ----------------
__global__ void bnrelu_kernel(float* __restrict__ h,
                              const float* __restrict__ scale,
                              const float* __restrict__ shift) {
    size_t idx = (size_t)blockIdx.x * blockDim.x + threadIdx.x;  // float4 index
    int j0 = ((int)idx & 63) * 4;
    float4 v = ((float4*)h)[idx];
    float4 sc = *(const float4*)&scale[j0];
    float4 sh = *(const float4*)&shift[j0];
    v.x = fmaxf(v.x * sc.x + sh.x, 0.f);
    v.y = fmaxf(v.y * sc.y + sh.y, 0.f);
    v.z = fmaxf(v.z * sc.z + sh.z, 0.f);
    v.w = fmaxf(v.w * sc.w + sh.w, 0.f);
    ((float4*)h)[idx] = v;
}

// ---------------- row L2 normalize (one wave per row) ----------------
__global__ void l2norm_kernel(float* __restrict__ out) {
    int wave = threadIdx.x >> 6;  // 0..3
    int lane = threadIdx.x & 63;
    for (int r = blockIdx.x * 4 + wave; r < NN; r += gridDim.x * 4) {
        float4 v = *(float4*)&out[(size_t)r * D + lane * 4];
        float sq = v.x * v.x + v.y * v.y + v.z * v.z + v.w * v.w;
#pragma unroll
        for (int o = 32; o; o >>= 1) sq += __shfl_xor(sq, o);
        float invn = 1.0f / fmaxf(sqrtf(sq), 1e-12f);
        v.x *= invn; v.y *= invn; v.z *= invn; v.w *= invn;
        *(float4*)&out[(size_t)r * D + lane * 4] = v;
    }
}

// ---------------- column sum of node_emb for pooling ----------------
__global__ void colsum_kernel(const float* __restrict__ h, float* __restrict__ gsum) {
    int j = threadIdx.x;
    float s0 = 0.f;
    for (int r = blockIdx.x; r < NN; r += gridDim.x) s0 += h[(size_t)r * D + j];
    atomicAdd(&gsum[j], s0);
}

// ---------------- final graph embedding ----------------
__global__ void graph_kernel(const float* __restrict__ gsum, float* __restrict__ gout) {
    __shared__ float wsum[4];
    int j = threadIdx.x;
    float v = gsum[j] * (1.0f / (float)NN);
    float sq = v * v;
#pragma unroll
    for (int o = 32; o; o >>= 1) sq += __shfl_xor(sq, o);
    if ((j & 63) == 0) wsum[j >> 6] = sq;
    __syncthreads();
    float tot = wsum[0] + wsum[1] + wsum[2] + wsum[3];
    gout[j] = v / fmaxf(sqrtf(tot), 1e-12f);
}

extern "C" void kernel_launch(void* const* d_in, const int* in_sizes, int n_in,
                              void* d_out, int out_size, void* d_ws, size_t ws_size,
                              hipStream_t stream) {
    const float* x      = (const float*)d_in[0];
    const float* W1_l   = (const float*)d_in[1];
    const float* b1_l   = (const float*)d_in[2];
    const float* W1_r   = (const float*)d_in[3];
    const float* W2_l   = (const float*)d_in[4];
    const float* b2_l   = (const float*)d_in[5];
    const float* W2_r   = (const float*)d_in[6];
    const float* gamma1 = (const float*)d_in[7];
    const float* beta1  = (const float*)d_in[8];
    const int*   eidx   = (const int*)d_in[9];
    const int* src = eidx;
    const int* dst = eidx + NE;

    // workspace layout (element offsets from base)
    int*   ws_i   = (int*)d_ws;
    int*   deg    = ws_i;                 // [NN]
    int*   offs   = ws_i + NN;            // [NN+1]
    int*   cur    = ws_i + 2 * NN + 8;    // [NN]
    int*   csr    = ws_i + 3 * NN + 16;   // [NE]
    float* ws_f   = (float*)d_ws;
    float* stats  = ws_f + 950272;        // [512]
    float* gsum   = stats + 512;          // [256]
    float* scale  = gsum + 256;           // [256]
    float* shift  = scale + 256;          // [256]
    float* s      = ws_f + 951552;        // [NN*D]
    float* h1     = s + (size_t)NN * D;   // [NN*D]
    float* out    = (float*)d_out;
    float* gout   = out + (size_t)NN * D;

    hipMemsetAsync(deg, 0, NN * sizeof(int), stream);
    hipMemsetAsync(stats, 0, 1280 * sizeof(float), stream);

    // CSR build (shared by both layers)
    degree_kernel<<<(NE + 255) / 256, 256, 0, stream>>>(dst, deg);
    scan_kernel<<<1, 1024, 0, stream>>>(deg, offs);
    cursor_kernel<<<(NN + 255) / 256, 256, 0, stream>>>(offs, cur);
    fill_kernel<<<(NE + 255) / 256, 256, 0, stream>>>(src, dst, cur, csr);

    dim3 ggrid((NN + BM - 1) / BM, D / BN);
    const int agg_blocks = (NN * 64 + 255) / 256;

    // layer 1
    agg_kernel<<<agg_blocks, 256, 0, stream>>>(x, csr, offs, s);
    sage_gemm_kernel<<<ggrid, 256, 0, stream>>>(s, x, W1_l, W1_r, b1_l, h1);
    colstats_kernel<<<256, D, 0, stream>>>(h1, stats);
    bnfin_kernel<<<1, D, 0, stream>>>(stats, gamma1, beta1, scale, shift);
    bnrelu_kernel<<<12500, 256, 0, stream>>>(h1, scale, shift);

    // layer 2
    agg_kernel<<<agg_blocks, 256, 0, stream>>>(h1, csr, offs, s);
    sage_gemm_kernel<<<ggrid, 256, 0, stream>>>(s, h1, W2_l, W2_r, b2_l, out);

    // outputs
    l2norm_kernel<<<2048, 256, 0, stream>>>(out);
    colsum_kernel<<<256, D, 0, stream>>>(out, gsum);
    graph_kernel<<<1, D, 0, stream>>>(gsum, gout);
}

// Round 3
// 531.433 us; speedup vs baseline: 3.6064x; 1.7390x over previous
//
#include <hip/hip_runtime.h>
#include <math.h>

#define NN 50000
#define NE 800000
#define D  256

typedef unsigned short u16;
typedef __attribute__((ext_vector_type(8))) short short8;
typedef __attribute__((ext_vector_type(8))) unsigned short u16x8;
typedef __attribute__((ext_vector_type(4))) float f32x4;

// f32 -> bf16 round-to-nearest-even
__device__ __forceinline__ u16 f2b(float f) {
    unsigned u = __float_as_uint(f);
    return (u16)((u + 0x7FFFu + ((u >> 16) & 1u)) >> 16);
}
__device__ __forceinline__ float b2f(u16 b) {
    return __uint_as_float(((unsigned)b) << 16);
}

// ---------------- CSR build ----------------
__global__ void degree_kernel(const int* __restrict__ dst, int* __restrict__ deg) {
    int e = blockIdx.x * blockDim.x + threadIdx.x;
    if (e < NE) atomicAdd(&deg[dst[e]], 1);
}

__global__ __launch_bounds__(1024)
void scan_kernel(const int* __restrict__ deg, int* __restrict__ offs) {
    __shared__ int sm[1024];
    const int t = threadIdx.x;
    const int C = (NN + 1023) / 1024;
    const int start = t * C;
    const int end = min(start + C, NN);
    int local = 0;
    for (int i = start; i < end; i++) local += deg[i];
    sm[t] = local;
    __syncthreads();
    for (int off = 1; off < 1024; off <<= 1) {
        int v = 0;
        if (t >= off) v = sm[t - off];
        __syncthreads();
        sm[t] += v;
        __syncthreads();
    }
    int run = (t > 0) ? sm[t - 1] : 0;
    for (int i = start; i < end; i++) {
        offs[i] = run;
        run += deg[i];
    }
    if (t == 1023) offs[NN] = sm[1023];
}

__global__ void cursor_kernel(const int* __restrict__ offs, int* __restrict__ cur) {
    int i = blockIdx.x * blockDim.x + threadIdx.x;
    if (i < NN) cur[i] = offs[i];
}

__global__ void fill_kernel(const int* __restrict__ src, const int* __restrict__ dst,
                            int* __restrict__ cur, int* __restrict__ csr) {
    int e = blockIdx.x * blockDim.x + threadIdx.x;
    if (e < NE) {
        int pos = atomicAdd(&cur[dst[e]], 1);
        csr[pos] = src[e];
    }
}

// ---------------- weight pack: Wcat[c][0:256]=Wl[c], [256:512]=Wr[c] (bf16) ----
__global__ void wconv_kernel(const float* __restrict__ W1l, const float* __restrict__ W1r,
                             const float* __restrict__ W2l, const float* __restrict__ W2r,
                             u16* __restrict__ Wcat1, u16* __restrict__ Wcat2) {
    int r = blockIdx.x;
    int j = threadIdx.x;
    Wcat1[r * 512 + j]       = f2b(W1l[r * 256 + j]);
    Wcat1[r * 512 + 256 + j] = f2b(W1r[r * 256 + j]);
    Wcat2[r * 512 + j]       = f2b(W2l[r * 256 + j]);
    Wcat2[r * 512 + 256 + j] = f2b(W2r[r * 256 + j]);
}

// ---------------- x (f32) -> Acat right half (bf16) ----------------
__global__ void xconv_kernel(const float* __restrict__ x, u16* __restrict__ Acat) {
    int idx = blockIdx.x * blockDim.x + threadIdx.x;  // float4 index, NN*64 total
    int r = idx >> 6;
    int c4 = (idx & 63) * 4;
    float4 v = *(const float4*)&x[(size_t)r * 256 + c4];
    ushort4 o;
    o.x = f2b(v.x); o.y = f2b(v.y); o.z = f2b(v.z); o.w = f2b(v.w);
    *(ushort4*)&Acat[(size_t)r * 512 + 256 + c4] = o;
}

// ---------------- mean aggregation (bf16 in/out): one wave per node ----------
// reads Acat[.][256:512], writes Acat[.][0:256]
__global__ __launch_bounds__(256)
void agg_kernel(const u16* __restrict__ Acat, const int* __restrict__ csr,
                const int* __restrict__ offs, u16* __restrict__ AcatW) {
    int wid = (blockIdx.x * blockDim.x + threadIdx.x) >> 6;
    int lane = threadIdx.x & 63;
    if (wid >= NN) return;
    int beg = offs[wid];
    int end = offs[wid + 1];
    float a0 = 0.f, a1 = 0.f, a2 = 0.f, a3 = 0.f;
    int e = beg;
    for (; e + 1 < end; e += 2) {
        int s0 = csr[e];
        int s1 = csr[e + 1];
        ushort4 v0 = *(const ushort4*)&Acat[(size_t)s0 * 512 + 256 + lane * 4];
        ushort4 v1 = *(const ushort4*)&Acat[(size_t)s1 * 512 + 256 + lane * 4];
        a0 += b2f(v0.x) + b2f(v1.x);
        a1 += b2f(v0.y) + b2f(v1.y);
        a2 += b2f(v0.z) + b2f(v1.z);
        a3 += b2f(v0.w) + b2f(v1.w);
    }
    if (e < end) {
        int s0 = csr[e];
        ushort4 v0 = *(const ushort4*)&Acat[(size_t)s0 * 512 + 256 + lane * 4];
        a0 += b2f(v0.x); a1 += b2f(v0.y); a2 += b2f(v0.z); a3 += b2f(v0.w);
    }
    int c = end - beg;
    float sc = (c > 0) ? 1.0f / (float)c : 0.0f;
    ushort4 o;
    o.x = f2b(a0 * sc); o.y = f2b(a1 * sc); o.z = f2b(a2 * sc); o.w = f2b(a3 * sc);
    *(ushort4*)&AcatW[(size_t)wid * 512 + lane * 4] = o;
}

// ---------------- MFMA GEMM: C[M=NN][256] = A[NN][512] @ W[256][512]^T + bias
// 128x128 tile, 4 waves (each 64x64 = 4x4 frags of 16x16), BK=32, 16 K-steps.
// LDS XOR swizzle: data (row, kg) stored at kslot = kg ^ ((row>>1)&3)  (2-way = free)
__global__ __launch_bounds__(256)
void mfma_gemm_kernel(const u16* __restrict__ A, const u16* __restrict__ W,
                      const float* __restrict__ bias, void* __restrict__ Cout,
                      int bf16_out) {
    __shared__ u16 As[128 * 32];
    __shared__ u16 Bs[128 * 32];
    const int tid = threadIdx.x;
    const int l = tid & 63;
    const int wid = tid >> 6;
    const int wr = wid >> 1, wc = wid & 1;
    const int row0 = blockIdx.x * 128;
    const int col0 = blockIdx.y * 128;

    f32x4 acc[4][4] = {};

    for (int k0 = 0; k0 < 512; k0 += 32) {
        __syncthreads();  // previous iteration's frag reads complete
#pragma unroll
        for (int i = 0; i < 2; i++) {
            int row = (wid * 2 + i) * 16 + (l >> 2);
            int kg = (l & 3) ^ ((row >> 1) & 3);  // source k-group for slot (l&3)
            int ra = row0 + row;
            if (ra > NN - 1) ra = NN - 1;
            short8 av = *(const short8*)&A[(size_t)ra * 512 + k0 + kg * 8];
            *(short8*)&As[row * 32 + (l & 3) * 8] = av;
            short8 bv = *(const short8*)&W[(size_t)(col0 + row) * 512 + k0 + kg * 8];
            *(short8*)&Bs[row * 32 + (l & 3) * 8] = bv;
        }
        __syncthreads();

        short8 af[4], bf[4];
        const int kq = l >> 4;
        const int sw = ((l & 15) >> 1) & 3;  // (row>>1)&3 for row = base16 + (l&15)
#pragma unroll
        for (int m = 0; m < 4; m++) {
            int row = wr * 64 + m * 16 + (l & 15);
            af[m] = *(const short8*)&As[row * 32 + (kq ^ sw) * 8];
        }
#pragma unroll
        for (int n = 0; n < 4; n++) {
            int row = wc * 64 + n * 16 + (l & 15);
            bf[n] = *(const short8*)&Bs[row * 32 + (kq ^ sw) * 8];
        }
#pragma unroll
        for (int m = 0; m < 4; m++)
#pragma unroll
            for (int n = 0; n < 4; n++)
                acc[m][n] = __builtin_amdgcn_mfma_f32_16x16x32_bf16(
                    af[m], bf[n], acc[m][n], 0, 0, 0);
    }

    // epilogue: C/D layout col = lane&15, row = (lane>>4)*4 + j   [m89-verified]
    const int cq = l >> 4;
    const int cc = l & 15;
#pragma unroll
    for (int m = 0; m < 4; m++) {
#pragma unroll
        for (int n = 0; n < 4; n++) {
#pragma unroll
            for (int j = 0; j < 4; j++) {
                int r = row0 + wr * 64 + m * 16 + cq * 4 + j;
                int c = col0 + wc * 64 + n * 16 + cc;
                if (r < NN) {
                    float v = acc[m][n][j] + bias[c];
                    if (bf16_out)
                        ((u16*)Cout)[(size_t)r * 256 + c] = f2b(v);
                    else
                        ((float*)Cout)[(size_t)r * 256 + c] = v;
                }
            }
        }
    }
}

// ---------------- per-column sum & sumsq for BN (bf16 input) ----------------
__global__ void colstats_kernel(const u16* __restrict__ h, float* __restrict__ stats) {
    int j = threadIdx.x;
    float s0 = 0.f, s1 = 0.f;
    for (int r = blockIdx.x; r < NN; r += gridDim.x) {
        float v = b2f(h[(size_t)r * 256 + j]);
        s0 += v;
        s1 += v * v;
    }
    atomicAdd(&stats[j], s0);
    atomicAdd(&stats[256 + j], s1);
}

__global__ void bnfin_kernel(const float* __restrict__ stats,
                             const float* __restrict__ gamma,
                             const float* __restrict__ beta,
                             float* __restrict__ scale,
                             float* __restrict__ shift) {
    int j = threadIdx.x;
    const float invN = 1.0f / (float)NN;
    float mu = stats[j] * invN;
    float var = stats[256 + j] * invN - mu * mu;
    float sc = gamma[j] * rsqrtf(var + 1e-5f);
    scale[j] = sc;
    shift[j] = beta[j] - mu * sc;
}

// ---------------- BN + ReLU: hb (bf16) -> Acat right half (bf16) ------------
__global__ void bnrelu_kernel(const u16* __restrict__ hb,
                              const float* __restrict__ scale,
                              const float* __restrict__ shift,
                              u16* __restrict__ Acat) {
    int idx = blockIdx.x * blockDim.x + threadIdx.x;  // u16x8 index, NN*32 total
    int r = idx >> 5;
    int c8 = (idx & 31) * 8;
    u16x8 v = *(const u16x8*)&hb[(size_t)r * 256 + c8];
    u16x8 o;
#pragma unroll
    for (int i = 0; i < 8; i++) {
        float f = b2f(v[i]) * scale[c8 + i] + shift[c8 + i];
        o[i] = f2b(fmaxf(f, 0.f));
    }
    *(u16x8*)&Acat[(size_t)r * 512 + 256 + c8] = o;
}

// ---------------- row L2 normalize (one wave per row), f32 in place ---------
__global__ void l2norm_kernel(float* __restrict__ out) {
    int wave = threadIdx.x >> 6;
    int lane = threadIdx.x & 63;
    for (int r = blockIdx.x * 4 + wave; r < NN; r += gridDim.x * 4) {
        float4 v = *(float4*)&out[(size_t)r * 256 + lane * 4];
        float sq = v.x * v.x + v.y * v.y + v.z * v.z + v.w * v.w;
#pragma unroll
        for (int o = 32; o; o >>= 1) sq += __shfl_xor(sq, o);
        float invn = 1.0f / fmaxf(sqrtf(sq), 1e-12f);
        v.x *= invn; v.y *= invn; v.z *= invn; v.w *= invn;
        *(float4*)&out[(size_t)r * 256 + lane * 4] = v;
    }
}

__global__ void colsum_kernel(const float* __restrict__ h, float* __restrict__ gsum) {
    int j = threadIdx.x;
    float s0 = 0.f;
    for (int r = blockIdx.x; r < NN; r += gridDim.x) s0 += h[(size_t)r * 256 + j];
    atomicAdd(&gsum[j], s0);
}

__global__ void graph_kernel(const float* __restrict__ gsum, float* __restrict__ gout) {
    __shared__ float wsum[4];
    int j = threadIdx.x;
    float v = gsum[j] * (1.0f / (float)NN);
    float sq = v * v;
#pragma unroll
    for (int o = 32; o; o >>= 1) sq += __shfl_xor(sq, o);
    if ((j & 63) == 0) wsum[j >> 6] = sq;
    __syncthreads();
    float tot = wsum[0] + wsum[1] + wsum[2] + wsum[3];
    gout[j] = v / fmaxf(sqrtf(tot), 1e-12f);
}

extern "C" void kernel_launch(void* const* d_in, const int* in_sizes, int n_in,
                              void* d_out, int out_size, void* d_ws, size_t ws_size,
                              hipStream_t stream) {
    const float* x      = (const float*)d_in[0];
    const float* W1_l   = (const float*)d_in[1];
    const float* b1_l   = (const float*)d_in[2];
    const float* W1_r   = (const float*)d_in[3];
    const float* W2_l   = (const float*)d_in[4];
    const float* b2_l   = (const float*)d_in[5];
    const float* W2_r   = (const float*)d_in[6];
    const float* gamma1 = (const float*)d_in[7];
    const float* beta1  = (const float*)d_in[8];
    const int*   eidx   = (const int*)d_in[9];
    const int* src = eidx;
    const int* dst = eidx + NE;

    // workspace layout (byte offsets), total ~81.2 MB
    char* wsb = (char*)d_ws;
    int*   deg   = (int*)(wsb + 0);          // [NN]
    int*   offs  = (int*)(wsb + 200000);     // [NN+1]
    int*   cur   = (int*)(wsb + 400004);     // [NN]
    int*   csr   = (int*)(wsb + 600004);     // [NE]
    float* stats = (float*)(wsb + 3800064);  // [512]
    float* gsum  = (float*)(wsb + 3802112);  // [256]
    float* scale = (float*)(wsb + 3803136);  // [256]
    float* shift = (float*)(wsb + 3804160);  // [256]
    u16*   Wcat1 = (u16*)(wsb + 3805184);    // [256*512]
    u16*   Wcat2 = (u16*)(wsb + 4067328);    // [256*512]
    u16*   hb    = (u16*)(wsb + 4329472);    // [NN*256]
    u16*   Acat  = (u16*)(wsb + 29929472);   // [NN*512]
    float* out   = (float*)d_out;
    float* gout  = out + (size_t)NN * 256;

    hipMemsetAsync(deg, 0, NN * sizeof(int), stream);
    hipMemsetAsync(stats, 0, 3072, stream);  // stats + gsum

    // packing / conversion
    wconv_kernel<<<256, 256, 0, stream>>>(W1_l, W1_r, W2_l, W2_r, Wcat1, Wcat2);
    xconv_kernel<<<12500, 256, 0, stream>>>(x, Acat);

    // CSR build (shared by both layers)
    degree_kernel<<<(NE + 255) / 256, 256, 0, stream>>>(dst, deg);
    scan_kernel<<<1, 1024, 0, stream>>>(deg, offs);
    cursor_kernel<<<(NN + 255) / 256, 256, 0, stream>>>(offs, cur);
    fill_kernel<<<(NE + 255) / 256, 256, 0, stream>>>(src, dst, cur, csr);

    dim3 ggrid((NN + 127) / 128, 2);

    // layer 1
    agg_kernel<<<12500, 256, 0, stream>>>(Acat, csr, offs, Acat);
    mfma_gemm_kernel<<<ggrid, 256, 0, stream>>>(Acat, Wcat1, b1_l, hb, 1);
    colstats_kernel<<<256, 256, 0, stream>>>(hb, stats);
    bnfin_kernel<<<1, 256, 0, stream>>>(stats, gamma1, beta1, scale, shift);
    bnrelu_kernel<<<6250, 256, 0, stream>>>(hb, scale, shift, Acat);

    // layer 2
    agg_kernel<<<12500, 256, 0, stream>>>(Acat, csr, offs, Acat);
    mfma_gemm_kernel<<<ggrid, 256, 0, stream>>>(Acat, Wcat2, b2_l, out, 0);

    // outputs
    l2norm_kernel<<<2048, 256, 0, stream>>>(out);
    colsum_kernel<<<256, 256, 0, stream>>>(out, gsum);
    graph_kernel<<<1, 256, 0, stream>>>(gsum, gout);
}

// Round 4
// 523.548 us; speedup vs baseline: 3.6607x; 1.0151x over previous
//
#include <hip/hip_runtime.h>
#include <math.h>

#define NN 50000
#define NE 800000
#define D  256
#define SCB 196  // ceil(NN/256)

typedef unsigned short u16;
typedef __attribute__((ext_vector_type(8))) short short8;
typedef __attribute__((ext_vector_type(8))) unsigned short u16x8;
typedef __attribute__((ext_vector_type(4))) float f32x4;

// f32 -> bf16 round-to-nearest-even
__device__ __forceinline__ u16 f2b(float f) {
    unsigned u = __float_as_uint(f);
    return (u16)((u + 0x7FFFu + ((u >> 16) & 1u)) >> 16);
}
__device__ __forceinline__ float b2f(u16 b) {
    return __uint_as_float(((unsigned)b) << 16);
}

// ---------------- CSR build ----------------
__global__ void degree_kernel(const int* __restrict__ dst, int* __restrict__ deg) {
    int e = blockIdx.x * blockDim.x + threadIdx.x;
    if (e < NE) atomicAdd(&deg[dst[e]], 1);
}

// partial[b] = sum of deg over block b's 256 elements
__global__ void scanA_kernel(const int* __restrict__ deg, int* __restrict__ partial) {
    int t = threadIdx.x;
    int i = blockIdx.x * 256 + t;
    int v = (i < NN) ? deg[i] : 0;
#pragma unroll
    for (int o = 32; o; o >>= 1) v += __shfl_xor(v, o);
    __shared__ int sm[4];
    if ((t & 63) == 0) sm[t >> 6] = v;
    __syncthreads();
    if (t == 0) partial[blockIdx.x] = sm[0] + sm[1] + sm[2] + sm[3];
}

// single small block: base = exclusive_scan(partial); offs[NN] = total
__global__ void scanB_kernel(const int* __restrict__ partial, int* __restrict__ base,
                             int* __restrict__ offs) {
    __shared__ int sm[256];
    int t = threadIdx.x;
    int v = (t < SCB) ? partial[t] : 0;
    sm[t] = v;
    __syncthreads();
    for (int off = 1; off < 256; off <<= 1) {
        int u = 0;
        if (t >= off) u = sm[t - off];
        __syncthreads();
        sm[t] += u;
        __syncthreads();
    }
    if (t < SCB) base[t] = sm[t] - v;
    if (t == 255) offs[NN] = sm[255];
}

// offs[i] = base[b] + exclusive_scan_within_block(deg); cur[i] = offs[i]
__global__ void scanC_kernel(const int* __restrict__ deg, const int* __restrict__ base,
                             int* __restrict__ offs, int* __restrict__ cur) {
    __shared__ int sm[256];
    int t = threadIdx.x;
    int i = blockIdx.x * 256 + t;
    int v = (i < NN) ? deg[i] : 0;
    sm[t] = v;
    __syncthreads();
    for (int off = 1; off < 256; off <<= 1) {
        int u = 0;
        if (t >= off) u = sm[t - off];
        __syncthreads();
        sm[t] += u;
        __syncthreads();
    }
    int o = base[blockIdx.x] + sm[t] - v;
    if (i < NN) {
        offs[i] = o;
        cur[i] = o;
    }
}

__global__ void fill_kernel(const int* __restrict__ src, const int* __restrict__ dst,
                            int* __restrict__ cur, int* __restrict__ csr) {
    int e = blockIdx.x * blockDim.x + threadIdx.x;
    if (e < NE) {
        int pos = atomicAdd(&cur[dst[e]], 1);
        csr[pos] = src[e];
    }
}

// ---------------- weight pack: Wcat[c][0:256]=Wl[c], [256:512]=Wr[c] (bf16) ----
__global__ void wconv_kernel(const float* __restrict__ W1l, const float* __restrict__ W1r,
                             const float* __restrict__ W2l, const float* __restrict__ W2r,
                             u16* __restrict__ Wcat1, u16* __restrict__ Wcat2) {
    int r = blockIdx.x;
    int j = threadIdx.x;
    Wcat1[r * 512 + j]       = f2b(W1l[r * 256 + j]);
    Wcat1[r * 512 + 256 + j] = f2b(W1r[r * 256 + j]);
    Wcat2[r * 512 + j]       = f2b(W2l[r * 256 + j]);
    Wcat2[r * 512 + 256 + j] = f2b(W2r[r * 256 + j]);
}

// ---------------- x (f32) -> Acat right half (bf16) ----------------
__global__ void xconv_kernel(const float* __restrict__ x, u16* __restrict__ Acat) {
    int idx = blockIdx.x * blockDim.x + threadIdx.x;  // float4 index, NN*64 total
    int r = idx >> 6;
    int c4 = (idx & 63) * 4;
    float4 v = *(const float4*)&x[(size_t)r * 256 + c4];
    ushort4 o;
    o.x = f2b(v.x); o.y = f2b(v.y); o.z = f2b(v.z); o.w = f2b(v.w);
    *(ushort4*)&Acat[(size_t)r * 512 + 256 + c4] = o;
}

// ---------------- mean aggregation (bf16): one wave per node, 2 edges in flight
// lanes 0-31 process even edges, 32-63 odd edges; lane covers 8 columns (16B).
__global__ __launch_bounds__(256)
void agg_kernel(const u16* __restrict__ Acat, const int* __restrict__ csr,
                const int* __restrict__ offs, u16* __restrict__ AcatW) {
    int wid = (blockIdx.x * blockDim.x + threadIdx.x) >> 6;
    int lane = threadIdx.x & 63;
    if (wid >= NN) return;
    int beg = offs[wid];
    int end = offs[wid + 1];
    int half = lane >> 5;
    int lc = (lane & 31) * 8;
    float a[8] = {0.f, 0.f, 0.f, 0.f, 0.f, 0.f, 0.f, 0.f};
    for (int e = beg + half; e < end; e += 2) {
        int s0 = csr[e];
        u16x8 v = *(const u16x8*)&Acat[(size_t)s0 * 512 + 256 + lc];
#pragma unroll
        for (int i = 0; i < 8; i++) a[i] += b2f(v[i]);
    }
#pragma unroll
    for (int i = 0; i < 8; i++) a[i] += __shfl_xor(a[i], 32);
    int c = end - beg;
    float sc = (c > 0) ? 1.0f / (float)c : 0.0f;
    if (half == 0) {
        u16x8 o;
#pragma unroll
        for (int i = 0; i < 8; i++) o[i] = f2b(a[i] * sc);
        *(u16x8*)&AcatW[(size_t)wid * 512 + lc] = o;
    }
}

// ---------------- MFMA GEMM: C[M=NN][256] = A[NN][512] @ W[256][512]^T + bias
__global__ __launch_bounds__(256)
void mfma_gemm_kernel(const u16* __restrict__ A, const u16* __restrict__ W,
                      const float* __restrict__ bias, void* __restrict__ Cout,
                      int bf16_out) {
    __shared__ u16 As[128 * 32];
    __shared__ u16 Bs[128 * 32];
    const int tid = threadIdx.x;
    const int l = tid & 63;
    const int wid = tid >> 6;
    const int wr = wid >> 1, wc = wid & 1;
    const int row0 = blockIdx.x * 128;
    const int col0 = blockIdx.y * 128;

    f32x4 acc[4][4] = {};

    for (int k0 = 0; k0 < 512; k0 += 32) {
        __syncthreads();
#pragma unroll
        for (int i = 0; i < 2; i++) {
            int row = (wid * 2 + i) * 16 + (l >> 2);
            int kg = (l & 3) ^ ((row >> 1) & 3);
            int ra = row0 + row;
            if (ra > NN - 1) ra = NN - 1;
            short8 av = *(const short8*)&A[(size_t)ra * 512 + k0 + kg * 8];
            *(short8*)&As[row * 32 + (l & 3) * 8] = av;
            short8 bv = *(const short8*)&W[(size_t)(col0 + row) * 512 + k0 + kg * 8];
            *(short8*)&Bs[row * 32 + (l & 3) * 8] = bv;
        }
        __syncthreads();

        short8 af[4], bf[4];
        const int kq = l >> 4;
        const int sw = ((l & 15) >> 1) & 3;
#pragma unroll
        for (int m = 0; m < 4; m++) {
            int row = wr * 64 + m * 16 + (l & 15);
            af[m] = *(const short8*)&As[row * 32 + (kq ^ sw) * 8];
        }
#pragma unroll
        for (int n = 0; n < 4; n++) {
            int row = wc * 64 + n * 16 + (l & 15);
            bf[n] = *(const short8*)&Bs[row * 32 + (kq ^ sw) * 8];
        }
#pragma unroll
        for (int m = 0; m < 4; m++)
#pragma unroll
            for (int n = 0; n < 4; n++)
                acc[m][n] = __builtin_amdgcn_mfma_f32_16x16x32_bf16(
                    af[m], bf[n], acc[m][n], 0, 0, 0);
    }

    const int cq = l >> 4;
    const int cc = l & 15;
#pragma unroll
    for (int m = 0; m < 4; m++) {
#pragma unroll
        for (int n = 0; n < 4; n++) {
#pragma unroll
            for (int j = 0; j < 4; j++) {
                int r = row0 + wr * 64 + m * 16 + cq * 4 + j;
                int c = col0 + wc * 64 + n * 16 + cc;
                if (r < NN) {
                    float v = acc[m][n][j] + bias[c];
                    if (bf16_out)
                        ((u16*)Cout)[(size_t)r * 256 + c] = f2b(v);
                    else
                        ((float*)Cout)[(size_t)r * 256 + c] = v;
                }
            }
        }
    }
}

// ---------------- per-column sum & sumsq for BN (bf16 input) ----------------
__global__ void colstats_kernel(const u16* __restrict__ h, float* __restrict__ stats) {
    int j = threadIdx.x;
    float s0 = 0.f, s1 = 0.f;
    for (int r = blockIdx.x; r < NN; r += gridDim.x) {
        float v = b2f(h[(size_t)r * 256 + j]);
        s0 += v;
        s1 += v * v;
    }
    atomicAdd(&stats[j], s0);
    atomicAdd(&stats[256 + j], s1);
}

__global__ void bnfin_kernel(const float* __restrict__ stats,
                             const float* __restrict__ gamma,
                             const float* __restrict__ beta,
                             float* __restrict__ scale,
                             float* __restrict__ shift) {
    int j = threadIdx.x;
    const float invN = 1.0f / (float)NN;
    float mu = stats[j] * invN;
    float var = stats[256 + j] * invN - mu * mu;
    float sc = gamma[j] * rsqrtf(var + 1e-5f);
    scale[j] = sc;
    shift[j] = beta[j] - mu * sc;
}

// ---------------- BN + ReLU: hb (bf16) -> Acat right half (bf16) ------------
__global__ void bnrelu_kernel(const u16* __restrict__ hb,
                              const float* __restrict__ scale,
                              const float* __restrict__ shift,
                              u16* __restrict__ Acat) {
    int idx = blockIdx.x * blockDim.x + threadIdx.x;  // u16x8 index, NN*32 total
    int r = idx >> 5;
    int c8 = (idx & 31) * 8;
    u16x8 v = *(const u16x8*)&hb[(size_t)r * 256 + c8];
    u16x8 o;
#pragma unroll
    for (int i = 0; i < 8; i++) {
        float f = b2f(v[i]) * scale[c8 + i] + shift[c8 + i];
        o[i] = f2b(fmaxf(f, 0.f));
    }
    *(u16x8*)&Acat[(size_t)r * 512 + 256 + c8] = o;
}

// ---------------- row L2 normalize + column-sum accumulate ------------------
__global__ __launch_bounds__(256)
void l2norm_kernel(float* __restrict__ out, float* __restrict__ gsum) {
    int wave = threadIdx.x >> 6;
    int lane = threadIdx.x & 63;
    float c0 = 0.f, c1 = 0.f, c2 = 0.f, c3 = 0.f;
    for (int r = blockIdx.x * 4 + wave; r < NN; r += gridDim.x * 4) {
        float4 v = *(float4*)&out[(size_t)r * 256 + lane * 4];
        float sq = v.x * v.x + v.y * v.y + v.z * v.z + v.w * v.w;
#pragma unroll
        for (int o = 32; o; o >>= 1) sq += __shfl_xor(sq, o);
        float invn = 1.0f / fmaxf(sqrtf(sq), 1e-12f);
        v.x *= invn; v.y *= invn; v.z *= invn; v.w *= invn;
        *(float4*)&out[(size_t)r * 256 + lane * 4] = v;
        c0 += v.x; c1 += v.y; c2 += v.z; c3 += v.w;
    }
    atomicAdd(&gsum[lane * 4 + 0], c0);
    atomicAdd(&gsum[lane * 4 + 1], c1);
    atomicAdd(&gsum[lane * 4 + 2], c2);
    atomicAdd(&gsum[lane * 4 + 3], c3);
}

__global__ void graph_kernel(const float* __restrict__ gsum, float* __restrict__ gout) {
    __shared__ float wsum[4];
    int j = threadIdx.x;
    float v = gsum[j] * (1.0f / (float)NN);
    float sq = v * v;
#pragma unroll
    for (int o = 32; o; o >>= 1) sq += __shfl_xor(sq, o);
    if ((j & 63) == 0) wsum[j >> 6] = sq;
    __syncthreads();
    float tot = wsum[0] + wsum[1] + wsum[2] + wsum[3];
    gout[j] = v / fmaxf(sqrtf(tot), 1e-12f);
}

extern "C" void kernel_launch(void* const* d_in, const int* in_sizes, int n_in,
                              void* d_out, int out_size, void* d_ws, size_t ws_size,
                              hipStream_t stream) {
    const float* x      = (const float*)d_in[0];
    const float* W1_l   = (const float*)d_in[1];
    const float* b1_l   = (const float*)d_in[2];
    const float* W1_r   = (const float*)d_in[3];
    const float* W2_l   = (const float*)d_in[4];
    const float* b2_l   = (const float*)d_in[5];
    const float* W2_r   = (const float*)d_in[6];
    const float* gamma1 = (const float*)d_in[7];
    const float* beta1  = (const float*)d_in[8];
    const int*   eidx   = (const int*)d_in[9];
    const int* src = eidx;
    const int* dst = eidx + NE;

    // workspace layout (byte offsets)
    char* wsb = (char*)d_ws;
    int*   deg   = (int*)(wsb + 0);          // [NN]
    int*   offs  = (int*)(wsb + 200000);     // [NN+1]
    int*   cur   = (int*)(wsb + 400004);     // [NN]
    int*   csr   = (int*)(wsb + 600004);     // [NE]
    int*   part  = (int*)(wsb + 3800064);    // [256]
    int*   base  = (int*)(wsb + 3801088);    // [256]
    float* stats = (float*)(wsb + 3802112);  // [512]
    float* gsum  = (float*)(wsb + 3804160);  // [256]
    float* scale = (float*)(wsb + 3805184);  // [256]
    float* shift = (float*)(wsb + 3806208);  // [256]
    u16*   Wcat1 = (u16*)(wsb + 3807232);    // [256*512]
    u16*   Wcat2 = (u16*)(wsb + 4069376);    // [256*512]
    u16*   hb    = (u16*)(wsb + 4331520);    // [NN*256]
    u16*   Acat  = (u16*)(wsb + 29931520);   // [NN*512]
    float* out   = (float*)d_out;
    float* gout  = out + (size_t)NN * 256;

    hipMemsetAsync(deg, 0, NN * sizeof(int), stream);
    hipMemsetAsync(stats, 0, 3072, stream);  // stats + gsum

    // packing / conversion
    wconv_kernel<<<256, 256, 0, stream>>>(W1_l, W1_r, W2_l, W2_r, Wcat1, Wcat2);
    xconv_kernel<<<12500, 256, 0, stream>>>(x, Acat);

    // CSR build (shared by both layers)
    degree_kernel<<<(NE + 255) / 256, 256, 0, stream>>>(dst, deg);
    scanA_kernel<<<SCB, 256, 0, stream>>>(deg, part);
    scanB_kernel<<<1, 256, 0, stream>>>(part, base, offs);
    scanC_kernel<<<SCB, 256, 0, stream>>>(deg, base, offs, cur);
    fill_kernel<<<(NE + 255) / 256, 256, 0, stream>>>(src, dst, cur, csr);

    dim3 ggrid((NN + 127) / 128, 2);

    // layer 1
    agg_kernel<<<12500, 256, 0, stream>>>(Acat, csr, offs, Acat);
    mfma_gemm_kernel<<<ggrid, 256, 0, stream>>>(Acat, Wcat1, b1_l, hb, 1);
    colstats_kernel<<<256, 256, 0, stream>>>(hb, stats);
    bnfin_kernel<<<1, 256, 0, stream>>>(stats, gamma1, beta1, scale, shift);
    bnrelu_kernel<<<6250, 256, 0, stream>>>(hb, scale, shift, Acat);

    // layer 2
    agg_kernel<<<12500, 256, 0, stream>>>(Acat, csr, offs, Acat);
    mfma_gemm_kernel<<<ggrid, 256, 0, stream>>>(Acat, Wcat2, b2_l, out, 0);

    // outputs
    l2norm_kernel<<<256, 256, 0, stream>>>(out, gsum);
    graph_kernel<<<1, 256, 0, stream>>>(gsum, gout);
}

// Round 5
// 409.798 us; speedup vs baseline: 4.6768x; 1.2776x over previous
//
#include <hip/hip_runtime.h>
#include <math.h>

#define NN 50000
#define NE 800000
#define D  256
#define SCB 196  // ceil(NN/256)

typedef unsigned short u16;
typedef __attribute__((ext_vector_type(8))) short short8;
typedef __attribute__((ext_vector_type(8))) unsigned short u16x8;
typedef __attribute__((ext_vector_type(4))) float f32x4;

// f32 -> bf16 round-to-nearest-even
__device__ __forceinline__ u16 f2b(float f) {
    unsigned u = __float_as_uint(f);
    return (u16)((u + 0x7FFFu + ((u >> 16) & 1u)) >> 16);
}
__device__ __forceinline__ float b2f(u16 b) {
    return __uint_as_float(((unsigned)b) << 16);
}

// ---------------- CSR build ----------------
__global__ void degree_kernel(const int* __restrict__ dst, int* __restrict__ deg) {
    int e = blockIdx.x * blockDim.x + threadIdx.x;
    if (e < NE) atomicAdd(&deg[dst[e]], 1);
}

__global__ void scanA_kernel(const int* __restrict__ deg, int* __restrict__ partial) {
    int t = threadIdx.x;
    int i = blockIdx.x * 256 + t;
    int v = (i < NN) ? deg[i] : 0;
#pragma unroll
    for (int o = 32; o; o >>= 1) v += __shfl_xor(v, o);
    __shared__ int sm[4];
    if ((t & 63) == 0) sm[t >> 6] = v;
    __syncthreads();
    if (t == 0) partial[blockIdx.x] = sm[0] + sm[1] + sm[2] + sm[3];
}

__global__ void scanB_kernel(const int* __restrict__ partial, int* __restrict__ base,
                             int* __restrict__ offs) {
    __shared__ int sm[256];
    int t = threadIdx.x;
    int v = (t < SCB) ? partial[t] : 0;
    sm[t] = v;
    __syncthreads();
    for (int off = 1; off < 256; off <<= 1) {
        int u = 0;
        if (t >= off) u = sm[t - off];
        __syncthreads();
        sm[t] += u;
        __syncthreads();
    }
    if (t < SCB) base[t] = sm[t] - v;
    if (t == 255) offs[NN] = sm[255];
}

__global__ void scanC_kernel(const int* __restrict__ deg, const int* __restrict__ base,
                             int* __restrict__ offs, int* __restrict__ cur) {
    __shared__ int sm[256];
    int t = threadIdx.x;
    int i = blockIdx.x * 256 + t;
    int v = (i < NN) ? deg[i] : 0;
    sm[t] = v;
    __syncthreads();
    for (int off = 1; off < 256; off <<= 1) {
        int u = 0;
        if (t >= off) u = sm[t - off];
        __syncthreads();
        sm[t] += u;
        __syncthreads();
    }
    int o = base[blockIdx.x] + sm[t] - v;
    if (i < NN) {
        offs[i] = o;
        cur[i] = o;
    }
}

__global__ void fill_kernel(const int* __restrict__ src, const int* __restrict__ dst,
                            int* __restrict__ cur, int* __restrict__ csr) {
    int e = blockIdx.x * blockDim.x + threadIdx.x;
    if (e < NE) {
        int pos = atomicAdd(&cur[dst[e]], 1);
        csr[pos] = src[e];
    }
}

// ---------------- weight pack ----------------
__global__ void wconv_kernel(const float* __restrict__ W1l, const float* __restrict__ W1r,
                             const float* __restrict__ W2l, const float* __restrict__ W2r,
                             u16* __restrict__ Wcat1, u16* __restrict__ Wcat2) {
    int r = blockIdx.x;
    int j = threadIdx.x;
    Wcat1[r * 512 + j]       = f2b(W1l[r * 256 + j]);
    Wcat1[r * 512 + 256 + j] = f2b(W1r[r * 256 + j]);
    Wcat2[r * 512 + j]       = f2b(W2l[r * 256 + j]);
    Wcat2[r * 512 + 256 + j] = f2b(W2r[r * 256 + j]);
}

// ---------------- x (f32) -> Acat right half (bf16) ----------------
__global__ void xconv_kernel(const float* __restrict__ x, u16* __restrict__ Acat) {
    int idx = blockIdx.x * blockDim.x + threadIdx.x;
    int r = idx >> 6;
    int c4 = (idx & 63) * 4;
    float4 v = *(const float4*)&x[(size_t)r * 256 + c4];
    ushort4 o;
    o.x = f2b(v.x); o.y = f2b(v.y); o.z = f2b(v.z); o.w = f2b(v.w);
    *(ushort4*)&Acat[(size_t)r * 512 + 256 + c4] = o;
}

// ---------------- mean aggregation ----------------
__global__ __launch_bounds__(256)
void agg_kernel(const u16* __restrict__ Acat, const int* __restrict__ csr,
                const int* __restrict__ offs, u16* __restrict__ AcatW) {
    int wid = (blockIdx.x * blockDim.x + threadIdx.x) >> 6;
    int lane = threadIdx.x & 63;
    if (wid >= NN) return;
    int beg = offs[wid];
    int end = offs[wid + 1];
    int half = lane >> 5;
    int lc = (lane & 31) * 8;
    float a[8] = {0.f, 0.f, 0.f, 0.f, 0.f, 0.f, 0.f, 0.f};
    for (int e = beg + half; e < end; e += 2) {
        int s0 = csr[e];
        u16x8 v = *(const u16x8*)&Acat[(size_t)s0 * 512 + 256 + lc];
#pragma unroll
        for (int i = 0; i < 8; i++) a[i] += b2f(v[i]);
    }
#pragma unroll
    for (int i = 0; i < 8; i++) a[i] += __shfl_xor(a[i], 32);
    int c = end - beg;
    float sc = (c > 0) ? 1.0f / (float)c : 0.0f;
    if (half == 0) {
        u16x8 o;
#pragma unroll
        for (int i = 0; i < 8; i++) o[i] = f2b(a[i] * sc);
        *(u16x8*)&AcatW[(size_t)wid * 512 + lc] = o;
    }
}

// ---------------- MFMA GEMM ----------------
__global__ __launch_bounds__(256)
void mfma_gemm_kernel(const u16* __restrict__ A, const u16* __restrict__ W,
                      const float* __restrict__ bias, void* __restrict__ Cout,
                      int bf16_out) {
    __shared__ u16 As[128 * 32];
    __shared__ u16 Bs[128 * 32];
    const int tid = threadIdx.x;
    const int l = tid & 63;
    const int wid = tid >> 6;
    const int wr = wid >> 1, wc = wid & 1;
    const int row0 = blockIdx.x * 128;
    const int col0 = blockIdx.y * 128;

    f32x4 acc[4][4] = {};

    for (int k0 = 0; k0 < 512; k0 += 32) {
        __syncthreads();
#pragma unroll
        for (int i = 0; i < 2; i++) {
            int row = (wid * 2 + i) * 16 + (l >> 2);
            int kg = (l & 3) ^ ((row >> 1) & 3);
            int ra = row0 + row;
            if (ra > NN - 1) ra = NN - 1;
            short8 av = *(const short8*)&A[(size_t)ra * 512 + k0 + kg * 8];
            *(short8*)&As[row * 32 + (l & 3) * 8] = av;
            short8 bv = *(const short8*)&W[(size_t)(col0 + row) * 512 + k0 + kg * 8];
            *(short8*)&Bs[row * 32 + (l & 3) * 8] = bv;
        }
        __syncthreads();

        short8 af[4], bf[4];
        const int kq = l >> 4;
        const int sw = ((l & 15) >> 1) & 3;
#pragma unroll
        for (int m = 0; m < 4; m++) {
            int row = wr * 64 + m * 16 + (l & 15);
            af[m] = *(const short8*)&As[row * 32 + (kq ^ sw) * 8];
        }
#pragma unroll
        for (int n = 0; n < 4; n++) {
            int row = wc * 64 + n * 16 + (l & 15);
            bf[n] = *(const short8*)&Bs[row * 32 + (kq ^ sw) * 8];
        }
#pragma unroll
        for (int m = 0; m < 4; m++)
#pragma unroll
            for (int n = 0; n < 4; n++)
                acc[m][n] = __builtin_amdgcn_mfma_f32_16x16x32_bf16(
                    af[m], bf[n], acc[m][n], 0, 0, 0);
    }

    const int cq = l >> 4;
    const int cc = l & 15;
#pragma unroll
    for (int m = 0; m < 4; m++) {
#pragma unroll
        for (int n = 0; n < 4; n++) {
#pragma unroll
            for (int j = 0; j < 4; j++) {
                int r = row0 + wr * 64 + m * 16 + cq * 4 + j;
                int c = col0 + wc * 64 + n * 16 + cc;
                if (r < NN) {
                    float v = acc[m][n][j] + bias[c];
                    if (bf16_out)
                        ((u16*)Cout)[(size_t)r * 256 + c] = f2b(v);
                    else
                        ((float*)Cout)[(size_t)r * 256 + c] = v;
                }
            }
        }
    }
}

// ---------------- per-column sum & sumsq for BN (bf16 input) ----------------
__global__ void colstats_kernel(const u16* __restrict__ h, float* __restrict__ stats) {
    int j = threadIdx.x;
    float s0 = 0.f, s1 = 0.f;
    for (int r = blockIdx.x; r < NN; r += gridDim.x) {
        float v = b2f(h[(size_t)r * 256 + j]);
        s0 += v;
        s1 += v * v;
    }
    atomicAdd(&stats[j], s0);
    atomicAdd(&stats[256 + j], s1);
}

__global__ void bnfin_kernel(const float* __restrict__ stats,
                             const float* __restrict__ gamma,
                             const float* __restrict__ beta,
                             float* __restrict__ scale,
                             float* __restrict__ shift) {
    int j = threadIdx.x;
    const float invN = 1.0f / (float)NN;
    float mu = stats[j] * invN;
    float var = stats[256 + j] * invN - mu * mu;
    float sc = gamma[j] * rsqrtf(var + 1e-5f);
    scale[j] = sc;
    shift[j] = beta[j] - mu * sc;
}

// ---------------- BN + ReLU ----------------
__global__ void bnrelu_kernel(const u16* __restrict__ hb,
                              const float* __restrict__ scale,
                              const float* __restrict__ shift,
                              u16* __restrict__ Acat) {
    int idx = blockIdx.x * blockDim.x + threadIdx.x;
    int r = idx >> 5;
    int c8 = (idx & 31) * 8;
    u16x8 v = *(const u16x8*)&hb[(size_t)r * 256 + c8];
    u16x8 o;
#pragma unroll
    for (int i = 0; i < 8; i++) {
        float f = b2f(v[i]) * scale[c8 + i] + shift[c8 + i];
        o[i] = f2b(fmaxf(f, 0.f));
    }
    *(u16x8*)&Acat[(size_t)r * 512 + 256 + c8] = o;
}

// ---------------- row L2 normalize + fused column-sum (512 blocks x 512 thr) --
__global__ __launch_bounds__(512)
void l2norm_kernel(float* __restrict__ out, float* __restrict__ gsum) {
    __shared__ float sm[8 * 256];
    int wave = threadIdx.x >> 6;   // 0..7
    int lane = threadIdx.x & 63;
    float c0 = 0.f, c1 = 0.f, c2 = 0.f, c3 = 0.f;
    for (int r = blockIdx.x * 8 + wave; r < NN; r += gridDim.x * 8) {
        float4 v = *(float4*)&out[(size_t)r * 256 + lane * 4];
        float sq = v.x * v.x + v.y * v.y + v.z * v.z + v.w * v.w;
#pragma unroll
        for (int o = 32; o; o >>= 1) sq += __shfl_xor(sq, o);
        float invn = 1.0f / fmaxf(sqrtf(sq), 1e-12f);
        v.x *= invn; v.y *= invn; v.z *= invn; v.w *= invn;
        *(float4*)&out[(size_t)r * 256 + lane * 4] = v;
        c0 += v.x; c1 += v.y; c2 += v.z; c3 += v.w;
    }
    *(float4*)&sm[wave * 256 + lane * 4] = make_float4(c0, c1, c2, c3);
    __syncthreads();
    int t = threadIdx.x;
    if (t < 256) {
        float s = 0.f;
#pragma unroll
        for (int w = 0; w < 8; w++) s += sm[w * 256 + t];
        atomicAdd(&gsum[t], s);
    }
}

__global__ void graph_kernel(const float* __restrict__ gsum, float* __restrict__ gout) {
    __shared__ float wsum[4];
    int j = threadIdx.x;
    float v = gsum[j] * (1.0f / (float)NN);
    float sq = v * v;
#pragma unroll
    for (int o = 32; o; o >>= 1) sq += __shfl_xor(sq, o);
    if ((j & 63) == 0) wsum[j >> 6] = sq;
    __syncthreads();
    float tot = wsum[0] + wsum[1] + wsum[2] + wsum[3];
    gout[j] = v / fmaxf(sqrtf(tot), 1e-12f);
}

extern "C" void kernel_launch(void* const* d_in, const int* in_sizes, int n_in,
                              void* d_out, int out_size, void* d_ws, size_t ws_size,
                              hipStream_t stream) {
    const float* x      = (const float*)d_in[0];
    const float* W1_l   = (const float*)d_in[1];
    const float* b1_l   = (const float*)d_in[2];
    const float* W1_r   = (const float*)d_in[3];
    const float* W2_l   = (const float*)d_in[4];
    const float* b2_l   = (const float*)d_in[5];
    const float* W2_r   = (const float*)d_in[6];
    const float* gamma1 = (const float*)d_in[7];
    const float* beta1  = (const float*)d_in[8];
    const int*   eidx   = (const int*)d_in[9];
    const int* src = eidx;
    const int* dst = eidx + NE;

    char* wsb = (char*)d_ws;
    int*   deg   = (int*)(wsb + 0);
    int*   offs  = (int*)(wsb + 200000);
    int*   cur   = (int*)(wsb + 400004);
    int*   csr   = (int*)(wsb + 600004);
    int*   part  = (int*)(wsb + 3800064);
    int*   base  = (int*)(wsb + 3801088);
    float* stats = (float*)(wsb + 3802112);
    float* gsum  = (float*)(wsb + 3804160);
    float* scale = (float*)(wsb + 3805184);
    float* shift = (float*)(wsb + 3806208);
    u16*   Wcat1 = (u16*)(wsb + 3807232);
    u16*   Wcat2 = (u16*)(wsb + 4069376);
    u16*   hb    = (u16*)(wsb + 4331520);
    u16*   Acat  = (u16*)(wsb + 29931520);
    float* out   = (float*)d_out;
    float* gout  = out + (size_t)NN * 256;

    hipMemsetAsync(deg, 0, NN * sizeof(int), stream);
    hipMemsetAsync(stats, 0, 3072, stream);  // stats + gsum

    wconv_kernel<<<256, 256, 0, stream>>>(W1_l, W1_r, W2_l, W2_r, Wcat1, Wcat2);
    xconv_kernel<<<12500, 256, 0, stream>>>(x, Acat);

    degree_kernel<<<(NE + 255) / 256, 256, 0, stream>>>(dst, deg);
    scanA_kernel<<<SCB, 256, 0, stream>>>(deg, part);
    scanB_kernel<<<1, 256, 0, stream>>>(part, base, offs);
    scanC_kernel<<<SCB, 256, 0, stream>>>(deg, base, offs, cur);
    fill_kernel<<<(NE + 255) / 256, 256, 0, stream>>>(src, dst, cur, csr);

    dim3 ggrid((NN + 127) / 128, 2);

    // layer 1
    agg_kernel<<<12500, 256, 0, stream>>>(Acat, csr, offs, Acat);
    mfma_gemm_kernel<<<ggrid, 256, 0, stream>>>(Acat, Wcat1, b1_l, hb, 1);
    colstats_kernel<<<512, 256, 0, stream>>>(hb, stats);
    bnfin_kernel<<<1, 256, 0, stream>>>(stats, gamma1, beta1, scale, shift);
    bnrelu_kernel<<<6250, 256, 0, stream>>>(hb, scale, shift, Acat);

    // layer 2
    agg_kernel<<<12500, 256, 0, stream>>>(Acat, csr, offs, Acat);
    mfma_gemm_kernel<<<ggrid, 256, 0, stream>>>(Acat, Wcat2, b2_l, out, 0);

    // outputs
    l2norm_kernel<<<512, 512, 0, stream>>>(out, gsum);
    graph_kernel<<<1, 256, 0, stream>>>(gsum, gout);
}

// Round 6
// 404.655 us; speedup vs baseline: 4.7363x; 1.0127x over previous
//
#include <hip/hip_runtime.h>
#include <math.h>

#define NN 50000
#define NE 800000
#define D  256
#define SCB 196  // ceil(NN/256)

typedef unsigned short u16;
typedef __attribute__((ext_vector_type(8))) short short8;
typedef __attribute__((ext_vector_type(8))) unsigned short u16x8;
typedef __attribute__((ext_vector_type(4))) float f32x4;

// f32 -> bf16 round-to-nearest-even
__device__ __forceinline__ u16 f2b(float f) {
    unsigned u = __float_as_uint(f);
    return (u16)((u + 0x7FFFu + ((u >> 16) & 1u)) >> 16);
}
__device__ __forceinline__ float b2f(u16 b) {
    return __uint_as_float(((unsigned)b) << 16);
}

// async global->LDS, 16 bytes per lane; LDS dest = wave-uniform base + lane*16
__device__ __forceinline__ void gl16(const u16* g, u16* l) {
    __builtin_amdgcn_global_load_lds(
        (const __attribute__((address_space(1))) void*)g,
        (__attribute__((address_space(3))) void*)l, 16, 0, 0);
}

// ---------------- CSR build ----------------
__global__ void degree_kernel(const int* __restrict__ dst, int* __restrict__ deg) {
    int e = blockIdx.x * blockDim.x + threadIdx.x;
    if (e < NE) atomicAdd(&deg[dst[e]], 1);
}

__global__ void scanA_kernel(const int* __restrict__ deg, int* __restrict__ partial) {
    int t = threadIdx.x;
    int i = blockIdx.x * 256 + t;
    int v = (i < NN) ? deg[i] : 0;
#pragma unroll
    for (int o = 32; o; o >>= 1) v += __shfl_xor(v, o);
    __shared__ int sm[4];
    if ((t & 63) == 0) sm[t >> 6] = v;
    __syncthreads();
    if (t == 0) partial[blockIdx.x] = sm[0] + sm[1] + sm[2] + sm[3];
}

__global__ void scanB_kernel(const int* __restrict__ partial, int* __restrict__ base,
                             int* __restrict__ offs) {
    __shared__ int sm[256];
    int t = threadIdx.x;
    int v = (t < SCB) ? partial[t] : 0;
    sm[t] = v;
    __syncthreads();
    for (int off = 1; off < 256; off <<= 1) {
        int u = 0;
        if (t >= off) u = sm[t - off];
        __syncthreads();
        sm[t] += u;
        __syncthreads();
    }
    if (t < SCB) base[t] = sm[t] - v;
    if (t == 255) offs[NN] = sm[255];
}

__global__ void scanC_kernel(const int* __restrict__ deg, const int* __restrict__ base,
                             int* __restrict__ offs, int* __restrict__ cur) {
    __shared__ int sm[256];
    int t = threadIdx.x;
    int i = blockIdx.x * 256 + t;
    int v = (i < NN) ? deg[i] : 0;
    sm[t] = v;
    __syncthreads();
    for (int off = 1; off < 256; off <<= 1) {
        int u = 0;
        if (t >= off) u = sm[t - off];
        __syncthreads();
        sm[t] += u;
        __syncthreads();
    }
    int o = base[blockIdx.x] + sm[t] - v;
    if (i < NN) {
        offs[i] = o;
        cur[i] = o;
    }
}

__global__ void fill_kernel(const int* __restrict__ src, const int* __restrict__ dst,
                            int* __restrict__ cur, int* __restrict__ csr) {
    int e = blockIdx.x * blockDim.x + threadIdx.x;
    if (e < NE) {
        int pos = atomicAdd(&cur[dst[e]], 1);
        csr[pos] = src[e];
    }
}

// ---------------- weight pack ----------------
__global__ void wconv_kernel(const float* __restrict__ W1l, const float* __restrict__ W1r,
                             const float* __restrict__ W2l, const float* __restrict__ W2r,
                             u16* __restrict__ Wcat1, u16* __restrict__ Wcat2) {
    int r = blockIdx.x;
    int j = threadIdx.x;
    Wcat1[r * 512 + j]       = f2b(W1l[r * 256 + j]);
    Wcat1[r * 512 + 256 + j] = f2b(W1r[r * 256 + j]);
    Wcat2[r * 512 + j]       = f2b(W2l[r * 256 + j]);
    Wcat2[r * 512 + 256 + j] = f2b(W2r[r * 256 + j]);
}

// ---------------- x (f32) -> Acat right half (bf16) ----------------
__global__ void xconv_kernel(const float* __restrict__ x, u16* __restrict__ Acat) {
    int idx = blockIdx.x * blockDim.x + threadIdx.x;
    int r = idx >> 6;
    int c4 = (idx & 63) * 4;
    float4 v = *(const float4*)&x[(size_t)r * 256 + c4];
    ushort4 o;
    o.x = f2b(v.x); o.y = f2b(v.y); o.z = f2b(v.z); o.w = f2b(v.w);
    *(ushort4*)&Acat[(size_t)r * 512 + 256 + c4] = o;
}

// ---------------- mean aggregation ----------------
__global__ __launch_bounds__(256)
void agg_kernel(const u16* __restrict__ Acat, const int* __restrict__ csr,
                const int* __restrict__ offs, u16* __restrict__ AcatW) {
    int wid = (blockIdx.x * blockDim.x + threadIdx.x) >> 6;
    int lane = threadIdx.x & 63;
    if (wid >= NN) return;
    int beg = offs[wid];
    int end = offs[wid + 1];
    int half = lane >> 5;
    int lc = (lane & 31) * 8;
    float a[8] = {0.f, 0.f, 0.f, 0.f, 0.f, 0.f, 0.f, 0.f};
    for (int e = beg + half; e < end; e += 2) {
        int s0 = csr[e];
        u16x8 v = *(const u16x8*)&Acat[(size_t)s0 * 512 + 256 + lc];
#pragma unroll
        for (int i = 0; i < 8; i++) a[i] += b2f(v[i]);
    }
#pragma unroll
    for (int i = 0; i < 8; i++) a[i] += __shfl_xor(a[i], 32);
    int c = end - beg;
    float sc = (c > 0) ? 1.0f / (float)c : 0.0f;
    if (half == 0) {
        u16x8 o;
#pragma unroll
        for (int i = 0; i < 8; i++) o[i] = f2b(a[i] * sc);
        *(u16x8*)&AcatW[(size_t)wid * 512 + lc] = o;
    }
}

// ---------------- MFMA GEMM: C[NN][256] = A[NN][512] @ W[256][512]^T + bias
// global_load_lds (16B) direct staging, double-buffered, 1 barrier per K-step.
// LDS swizzle kept via pre-swizzled global source: lane covering (row, slot)
// fetches k-group kg = slot ^ ((row>>1)&3); read side applies the same XOR.
template<int BF16_OUT>
__global__ __launch_bounds__(256)
void mfma_gemm_kernel(const u16* __restrict__ A, const u16* __restrict__ W,
                      const float* __restrict__ bias, void* __restrict__ Cout) {
    __shared__ u16 As[2][128 * 32];
    __shared__ u16 Bs[2][128 * 32];
    const int tid = threadIdx.x;
    const int l = tid & 63;
    const int wid = tid >> 6;
    const int wr = wid >> 1, wc = wid & 1;
    const int row0 = blockIdx.x * 128;
    const int col0 = blockIdx.y * 128;

    // per-lane global source pointers for the 2 staging insts (A and B)
    const u16* aptr[2];
    const u16* bptr[2];
#pragma unroll
    for (int i = 0; i < 2; i++) {
        int row = wid * 32 + i * 16 + (l >> 2);       // tile row this lane stages
        int kg = (l & 3) ^ ((row >> 1) & 3);          // pre-swizzled k-group
        int ra = row0 + row;
        if (ra > NN - 1) ra = NN - 1;
        aptr[i] = A + (size_t)ra * 512 + kg * 8;
        bptr[i] = W + (size_t)(col0 + row) * 512 + kg * 8;
    }

    f32x4 acc[4][4] = {};

#define STAGE(b, t)                                                          \
    do {                                                                     \
        _Pragma("unroll") for (int i_ = 0; i_ < 2; i_++) {                   \
            u16* al = &As[b][(wid * 32 + i_ * 16) * 32];                     \
            u16* bl = &Bs[b][(wid * 32 + i_ * 16) * 32];                     \
            gl16(aptr[i_] + (t) * 32, al);                                   \
            gl16(bptr[i_] + (t) * 32, bl);                                   \
        }                                                                    \
    } while (0)

    STAGE(0, 0);
    __syncthreads();

    int buf = 0;
    const int kq = l >> 4;
    const int sw = ((l & 15) >> 1) & 3;
#pragma unroll 4
    for (int t = 0; t < 16; t++) {
        if (t < 15) STAGE(buf ^ 1, t + 1);

        short8 af[4], bf[4];
#pragma unroll
        for (int m = 0; m < 4; m++) {
            int row = wr * 64 + m * 16 + (l & 15);
            af[m] = *(const short8*)&As[buf][row * 32 + (kq ^ sw) * 8];
        }
#pragma unroll
        for (int n = 0; n < 4; n++) {
            int row = wc * 64 + n * 16 + (l & 15);
            bf[n] = *(const short8*)&Bs[buf][row * 32 + (kq ^ sw) * 8];
        }
#pragma unroll
        for (int m = 0; m < 4; m++)
#pragma unroll
            for (int n = 0; n < 4; n++)
                acc[m][n] = __builtin_amdgcn_mfma_f32_16x16x32_bf16(
                    af[m], bf[n], acc[m][n], 0, 0, 0);

        __syncthreads();  // drains staging of t+1; protects buf reuse
        buf ^= 1;
    }
#undef STAGE

    const int cq = l >> 4;
    const int cc = l & 15;
#pragma unroll
    for (int m = 0; m < 4; m++) {
#pragma unroll
        for (int n = 0; n < 4; n++) {
#pragma unroll
            for (int j = 0; j < 4; j++) {
                int r = row0 + wr * 64 + m * 16 + cq * 4 + j;
                int c = col0 + wc * 64 + n * 16 + cc;
                if (r < NN) {
                    float v = acc[m][n][j] + bias[c];
                    if (BF16_OUT)
                        ((u16*)Cout)[(size_t)r * 256 + c] = f2b(v);
                    else
                        ((float*)Cout)[(size_t)r * 256 + c] = v;
                }
            }
        }
    }
}

// ---------------- per-column sum & sumsq for BN (bf16 input) ----------------
__global__ void colstats_kernel(const u16* __restrict__ h, float* __restrict__ stats) {
    int j = threadIdx.x;
    float s0 = 0.f, s1 = 0.f;
    for (int r = blockIdx.x; r < NN; r += gridDim.x) {
        float v = b2f(h[(size_t)r * 256 + j]);
        s0 += v;
        s1 += v * v;
    }
    atomicAdd(&stats[j], s0);
    atomicAdd(&stats[256 + j], s1);
}

__global__ void bnfin_kernel(const float* __restrict__ stats,
                             const float* __restrict__ gamma,
                             const float* __restrict__ beta,
                             float* __restrict__ scale,
                             float* __restrict__ shift) {
    int j = threadIdx.x;
    const float invN = 1.0f / (float)NN;
    float mu = stats[j] * invN;
    float var = stats[256 + j] * invN - mu * mu;
    float sc = gamma[j] * rsqrtf(var + 1e-5f);
    scale[j] = sc;
    shift[j] = beta[j] - mu * sc;
}

// ---------------- BN + ReLU ----------------
__global__ void bnrelu_kernel(const u16* __restrict__ hb,
                              const float* __restrict__ scale,
                              const float* __restrict__ shift,
                              u16* __restrict__ Acat) {
    int idx = blockIdx.x * blockDim.x + threadIdx.x;
    int r = idx >> 5;
    int c8 = (idx & 31) * 8;
    u16x8 v = *(const u16x8*)&hb[(size_t)r * 256 + c8];
    u16x8 o;
#pragma unroll
    for (int i = 0; i < 8; i++) {
        float f = b2f(v[i]) * scale[c8 + i] + shift[c8 + i];
        o[i] = f2b(fmaxf(f, 0.f));
    }
    *(u16x8*)&Acat[(size_t)r * 512 + 256 + c8] = o;
}

// ---------------- row L2 normalize + fused column-sum ------------------
__global__ __launch_bounds__(512)
void l2norm_kernel(float* __restrict__ out, float* __restrict__ gsum) {
    __shared__ float sm[8 * 256];
    int wave = threadIdx.x >> 6;   // 0..7
    int lane = threadIdx.x & 63;
    float c0 = 0.f, c1 = 0.f, c2 = 0.f, c3 = 0.f;
    for (int r = blockIdx.x * 8 + wave; r < NN; r += gridDim.x * 8) {
        float4 v = *(float4*)&out[(size_t)r * 256 + lane * 4];
        float sq = v.x * v.x + v.y * v.y + v.z * v.z + v.w * v.w;
#pragma unroll
        for (int o = 32; o; o >>= 1) sq += __shfl_xor(sq, o);
        float invn = 1.0f / fmaxf(sqrtf(sq), 1e-12f);
        v.x *= invn; v.y *= invn; v.z *= invn; v.w *= invn;
        *(float4*)&out[(size_t)r * 256 + lane * 4] = v;
        c0 += v.x; c1 += v.y; c2 += v.z; c3 += v.w;
    }
    *(float4*)&sm[wave * 256 + lane * 4] = make_float4(c0, c1, c2, c3);
    __syncthreads();
    int t = threadIdx.x;
    if (t < 256) {
        float s = 0.f;
#pragma unroll
        for (int w = 0; w < 8; w++) s += sm[w * 256 + t];
        atomicAdd(&gsum[t], s);
    }
}

__global__ void graph_kernel(const float* __restrict__ gsum, float* __restrict__ gout) {
    __shared__ float wsum[4];
    int j = threadIdx.x;
    float v = gsum[j] * (1.0f / (float)NN);
    float sq = v * v;
#pragma unroll
    for (int o = 32; o; o >>= 1) sq += __shfl_xor(sq, o);
    if ((j & 63) == 0) wsum[j >> 6] = sq;
    __syncthreads();
    float tot = wsum[0] + wsum[1] + wsum[2] + wsum[3];
    gout[j] = v / fmaxf(sqrtf(tot), 1e-12f);
}

extern "C" void kernel_launch(void* const* d_in, const int* in_sizes, int n_in,
                              void* d_out, int out_size, void* d_ws, size_t ws_size,
                              hipStream_t stream) {
    const float* x      = (const float*)d_in[0];
    const float* W1_l   = (const float*)d_in[1];
    const float* b1_l   = (const float*)d_in[2];
    const float* W1_r   = (const float*)d_in[3];
    const float* W2_l   = (const float*)d_in[4];
    const float* b2_l   = (const float*)d_in[5];
    const float* W2_r   = (const float*)d_in[6];
    const float* gamma1 = (const float*)d_in[7];
    const float* beta1  = (const float*)d_in[8];
    const int*   eidx   = (const int*)d_in[9];
    const int* src = eidx;
    const int* dst = eidx + NE;

    char* wsb = (char*)d_ws;
    int*   deg   = (int*)(wsb + 0);
    int*   offs  = (int*)(wsb + 200000);
    int*   cur   = (int*)(wsb + 400004);
    int*   csr   = (int*)(wsb + 600004);
    int*   part  = (int*)(wsb + 3800064);
    int*   base  = (int*)(wsb + 3801088);
    float* stats = (float*)(wsb + 3802112);
    float* gsum  = (float*)(wsb + 3804160);
    float* scale = (float*)(wsb + 3805184);
    float* shift = (float*)(wsb + 3806208);
    u16*   Wcat1 = (u16*)(wsb + 3807232);
    u16*   Wcat2 = (u16*)(wsb + 4069376);
    u16*   hb    = (u16*)(wsb + 4331520);
    u16*   Acat  = (u16*)(wsb + 29931520);
    float* out   = (float*)d_out;
    float* gout  = out + (size_t)NN * 256;

    hipMemsetAsync(deg, 0, NN * sizeof(int), stream);
    hipMemsetAsync(stats, 0, 3072, stream);  // stats + gsum

    wconv_kernel<<<256, 256, 0, stream>>>(W1_l, W1_r, W2_l, W2_r, Wcat1, Wcat2);
    xconv_kernel<<<12500, 256, 0, stream>>>(x, Acat);

    degree_kernel<<<(NE + 255) / 256, 256, 0, stream>>>(dst, deg);
    scanA_kernel<<<SCB, 256, 0, stream>>>(deg, part);
    scanB_kernel<<<1, 256, 0, stream>>>(part, base, offs);
    scanC_kernel<<<SCB, 256, 0, stream>>>(deg, base, offs, cur);
    fill_kernel<<<(NE + 255) / 256, 256, 0, stream>>>(src, dst, cur, csr);

    dim3 ggrid((NN + 127) / 128, 2);

    // layer 1
    agg_kernel<<<12500, 256, 0, stream>>>(Acat, csr, offs, Acat);
    mfma_gemm_kernel<1><<<ggrid, 256, 0, stream>>>(Acat, Wcat1, b1_l, hb);
    colstats_kernel<<<512, 256, 0, stream>>>(hb, stats);
    bnfin_kernel<<<1, 256, 0, stream>>>(stats, gamma1, beta1, scale, shift);
    bnrelu_kernel<<<6250, 256, 0, stream>>>(hb, scale, shift, Acat);

    // layer 2
    agg_kernel<<<12500, 256, 0, stream>>>(Acat, csr, offs, Acat);
    mfma_gemm_kernel<0><<<ggrid, 256, 0, stream>>>(Acat, Wcat2, b2_l, out);

    // outputs
    l2norm_kernel<<<512, 512, 0, stream>>>(out, gsum);
    graph_kernel<<<1, 256, 0, stream>>>(gsum, gout);
}

// Round 7
// 401.776 us; speedup vs baseline: 4.7702x; 1.0072x over previous
//
#include <hip/hip_runtime.h>
#include <math.h>

#define NN 50000
#define NE 800000
#define D  256
#define SCB 196  // ceil(NN/256)

typedef unsigned short u16;
typedef __attribute__((ext_vector_type(8))) short short8;
typedef __attribute__((ext_vector_type(8))) unsigned short u16x8;
typedef __attribute__((ext_vector_type(4))) float f32x4;

// f32 -> bf16 round-to-nearest-even
__device__ __forceinline__ u16 f2b(float f) {
    unsigned u = __float_as_uint(f);
    return (u16)((u + 0x7FFFu + ((u >> 16) & 1u)) >> 16);
}
__device__ __forceinline__ float b2f(u16 b) {
    return __uint_as_float(((unsigned)b) << 16);
}

// async global->LDS, 16 bytes per lane; LDS dest = wave-uniform base + lane*16
__device__ __forceinline__ void gl16(const u16* g, u16* l) {
    __builtin_amdgcn_global_load_lds(
        (const __attribute__((address_space(1))) void*)g,
        (__attribute__((address_space(3))) void*)l, 16, 0, 0);
}

// ---------------- CSR build ----------------
__global__ void degree_kernel(const int* __restrict__ dst, int* __restrict__ deg) {
    int e = blockIdx.x * blockDim.x + threadIdx.x;
    if (e < NE) atomicAdd(&deg[dst[e]], 1);
}

__global__ void scanA_kernel(const int* __restrict__ deg, int* __restrict__ partial) {
    int t = threadIdx.x;
    int i = blockIdx.x * 256 + t;
    int v = (i < NN) ? deg[i] : 0;
#pragma unroll
    for (int o = 32; o; o >>= 1) v += __shfl_xor(v, o);
    __shared__ int sm[4];
    if ((t & 63) == 0) sm[t >> 6] = v;
    __syncthreads();
    if (t == 0) partial[blockIdx.x] = sm[0] + sm[1] + sm[2] + sm[3];
}

__global__ void scanB_kernel(const int* __restrict__ partial, int* __restrict__ base,
                             int* __restrict__ offs) {
    __shared__ int sm[256];
    int t = threadIdx.x;
    int v = (t < SCB) ? partial[t] : 0;
    sm[t] = v;
    __syncthreads();
    for (int off = 1; off < 256; off <<= 1) {
        int u = 0;
        if (t >= off) u = sm[t - off];
        __syncthreads();
        sm[t] += u;
        __syncthreads();
    }
    if (t < SCB) base[t] = sm[t] - v;
    if (t == 255) offs[NN] = sm[255];
}

__global__ void scanC_kernel(const int* __restrict__ deg, const int* __restrict__ base,
                             int* __restrict__ offs, int* __restrict__ cur) {
    __shared__ int sm[256];
    int t = threadIdx.x;
    int i = blockIdx.x * 256 + t;
    int v = (i < NN) ? deg[i] : 0;
    sm[t] = v;
    __syncthreads();
    for (int off = 1; off < 256; off <<= 1) {
        int u = 0;
        if (t >= off) u = sm[t - off];
        __syncthreads();
        sm[t] += u;
        __syncthreads();
    }
    int o = base[blockIdx.x] + sm[t] - v;
    if (i < NN) {
        offs[i] = o;
        cur[i] = o;
    }
}

__global__ void fill_kernel(const int* __restrict__ src, const int* __restrict__ dst,
                            int* __restrict__ cur, int* __restrict__ csr) {
    int e = blockIdx.x * blockDim.x + threadIdx.x;
    if (e < NE) {
        int pos = atomicAdd(&cur[dst[e]], 1);
        csr[pos] = src[e];
    }
}

// ---------------- weight pack ----------------
__global__ void wconv_kernel(const float* __restrict__ W1l, const float* __restrict__ W1r,
                             const float* __restrict__ W2l, const float* __restrict__ W2r,
                             u16* __restrict__ Wcat1, u16* __restrict__ Wcat2) {
    int r = blockIdx.x;
    int j = threadIdx.x;
    Wcat1[r * 512 + j]       = f2b(W1l[r * 256 + j]);
    Wcat1[r * 512 + 256 + j] = f2b(W1r[r * 256 + j]);
    Wcat2[r * 512 + j]       = f2b(W2l[r * 256 + j]);
    Wcat2[r * 512 + 256 + j] = f2b(W2r[r * 256 + j]);
}

// ---------------- x (f32) -> Acat right half (bf16) ----------------
__global__ void xconv_kernel(const float* __restrict__ x, u16* __restrict__ Acat) {
    int idx = blockIdx.x * blockDim.x + threadIdx.x;
    int r = idx >> 6;
    int c4 = (idx & 63) * 4;
    float4 v = *(const float4*)&x[(size_t)r * 256 + c4];
    ushort4 o;
    o.x = f2b(v.x); o.y = f2b(v.y); o.z = f2b(v.z); o.w = f2b(v.w);
    *(ushort4*)&Acat[(size_t)r * 512 + 256 + c4] = o;
}

// ---------------- mean aggregation: one wave per node --------------------
// Each 32-lane half takes a CONTIGUOUS half of the edge list and keeps 4
// independent 16-B gathers in flight (64 B/lane outstanding).
__global__ __launch_bounds__(256)
void agg_kernel(const u16* __restrict__ Acat, const int* __restrict__ csr,
                const int* __restrict__ offs, u16* __restrict__ AcatW) {
    int wid = (blockIdx.x * blockDim.x + threadIdx.x) >> 6;
    int lane = threadIdx.x & 63;
    if (wid >= NN) return;
    int beg = offs[wid];
    int end = offs[wid + 1];
    int deg = end - beg;
    int half = lane >> 5;
    int lc = (lane & 31) * 8;
    int mid = beg + ((deg + 1) >> 1);
    int e  = half ? mid : beg;
    int hi = half ? end : mid;
    float a[8] = {0.f, 0.f, 0.f, 0.f, 0.f, 0.f, 0.f, 0.f};
    for (; e + 3 < hi; e += 4) {
        int s0 = csr[e + 0];
        int s1 = csr[e + 1];
        int s2 = csr[e + 2];
        int s3 = csr[e + 3];
        u16x8 v0 = *(const u16x8*)&Acat[(size_t)s0 * 512 + 256 + lc];
        u16x8 v1 = *(const u16x8*)&Acat[(size_t)s1 * 512 + 256 + lc];
        u16x8 v2 = *(const u16x8*)&Acat[(size_t)s2 * 512 + 256 + lc];
        u16x8 v3 = *(const u16x8*)&Acat[(size_t)s3 * 512 + 256 + lc];
#pragma unroll
        for (int i = 0; i < 8; i++)
            a[i] += (b2f(v0[i]) + b2f(v1[i])) + (b2f(v2[i]) + b2f(v3[i]));
    }
    for (; e < hi; e++) {
        int s0 = csr[e];
        u16x8 v0 = *(const u16x8*)&Acat[(size_t)s0 * 512 + 256 + lc];
#pragma unroll
        for (int i = 0; i < 8; i++) a[i] += b2f(v0[i]);
    }
#pragma unroll
    for (int i = 0; i < 8; i++) a[i] += __shfl_xor(a[i], 32);
    float sc = (deg > 0) ? 1.0f / (float)deg : 0.0f;
    if (half == 0) {
        u16x8 o;
#pragma unroll
        for (int i = 0; i < 8; i++) o[i] = f2b(a[i] * sc);
        *(u16x8*)&AcatW[(size_t)wid * 512 + lc] = o;
    }
}

// ---------------- MFMA GEMM: C[NN][256] = A[NN][512] @ W[256][512]^T + bias
template<int BF16_OUT>
__global__ __launch_bounds__(256)
void mfma_gemm_kernel(const u16* __restrict__ A, const u16* __restrict__ W,
                      const float* __restrict__ bias, void* __restrict__ Cout) {
    __shared__ u16 As[2][128 * 32];
    __shared__ u16 Bs[2][128 * 32];
    const int tid = threadIdx.x;
    const int l = tid & 63;
    const int wid = tid >> 6;
    const int wr = wid >> 1, wc = wid & 1;
    const int row0 = blockIdx.x * 128;
    const int col0 = blockIdx.y * 128;

    const u16* aptr[2];
    const u16* bptr[2];
#pragma unroll
    for (int i = 0; i < 2; i++) {
        int row = wid * 32 + i * 16 + (l >> 2);
        int kg = (l & 3) ^ ((row >> 1) & 3);
        int ra = row0 + row;
        if (ra > NN - 1) ra = NN - 1;
        aptr[i] = A + (size_t)ra * 512 + kg * 8;
        bptr[i] = W + (size_t)(col0 + row) * 512 + kg * 8;
    }

    f32x4 acc[4][4] = {};

#define STAGE(b, t)                                                          \
    do {                                                                     \
        _Pragma("unroll") for (int i_ = 0; i_ < 2; i_++) {                   \
            u16* al = &As[b][(wid * 32 + i_ * 16) * 32];                     \
            u16* bl = &Bs[b][(wid * 32 + i_ * 16) * 32];                     \
            gl16(aptr[i_] + (t) * 32, al);                                   \
            gl16(bptr[i_] + (t) * 32, bl);                                   \
        }                                                                    \
    } while (0)

    STAGE(0, 0);
    __syncthreads();

    int buf = 0;
    const int kq = l >> 4;
    const int sw = ((l & 15) >> 1) & 3;
#pragma unroll 4
    for (int t = 0; t < 16; t++) {
        if (t < 15) STAGE(buf ^ 1, t + 1);

        short8 af[4], bf[4];
#pragma unroll
        for (int m = 0; m < 4; m++) {
            int row = wr * 64 + m * 16 + (l & 15);
            af[m] = *(const short8*)&As[buf][row * 32 + (kq ^ sw) * 8];
        }
#pragma unroll
        for (int n = 0; n < 4; n++) {
            int row = wc * 64 + n * 16 + (l & 15);
            bf[n] = *(const short8*)&Bs[buf][row * 32 + (kq ^ sw) * 8];
        }
#pragma unroll
        for (int m = 0; m < 4; m++)
#pragma unroll
            for (int n = 0; n < 4; n++)
                acc[m][n] = __builtin_amdgcn_mfma_f32_16x16x32_bf16(
                    af[m], bf[n], acc[m][n], 0, 0, 0);

        __syncthreads();
        buf ^= 1;
    }
#undef STAGE

    const int cq = l >> 4;
    const int cc = l & 15;
#pragma unroll
    for (int m = 0; m < 4; m++) {
#pragma unroll
        for (int n = 0; n < 4; n++) {
#pragma unroll
            for (int j = 0; j < 4; j++) {
                int r = row0 + wr * 64 + m * 16 + cq * 4 + j;
                int c = col0 + wc * 64 + n * 16 + cc;
                if (r < NN) {
                    float v = acc[m][n][j] + bias[c];
                    if (BF16_OUT)
                        ((u16*)Cout)[(size_t)r * 256 + c] = f2b(v);
                    else
                        ((float*)Cout)[(size_t)r * 256 + c] = v;
                }
            }
        }
    }
}

// ---------------- per-column sum & sumsq for BN (bf16 input) ----------------
__global__ void colstats_kernel(const u16* __restrict__ h, float* __restrict__ stats) {
    int j = threadIdx.x;
    float s0 = 0.f, s1 = 0.f;
    for (int r = blockIdx.x; r < NN; r += gridDim.x) {
        float v = b2f(h[(size_t)r * 256 + j]);
        s0 += v;
        s1 += v * v;
    }
    atomicAdd(&stats[j], s0);
    atomicAdd(&stats[256 + j], s1);
}

__global__ void bnfin_kernel(const float* __restrict__ stats,
                             const float* __restrict__ gamma,
                             const float* __restrict__ beta,
                             float* __restrict__ scale,
                             float* __restrict__ shift) {
    int j = threadIdx.x;
    const float invN = 1.0f / (float)NN;
    float mu = stats[j] * invN;
    float var = stats[256 + j] * invN - mu * mu;
    float sc = gamma[j] * rsqrtf(var + 1e-5f);
    scale[j] = sc;
    shift[j] = beta[j] - mu * sc;
}

// ---------------- BN + ReLU ----------------
__global__ void bnrelu_kernel(const u16* __restrict__ hb,
                              const float* __restrict__ scale,
                              const float* __restrict__ shift,
                              u16* __restrict__ Acat) {
    int idx = blockIdx.x * blockDim.x + threadIdx.x;
    int r = idx >> 5;
    int c8 = (idx & 31) * 8;
    u16x8 v = *(const u16x8*)&hb[(size_t)r * 256 + c8];
    u16x8 o;
#pragma unroll
    for (int i = 0; i < 8; i++) {
        float f = b2f(v[i]) * scale[c8 + i] + shift[c8 + i];
        o[i] = f2b(fmaxf(f, 0.f));
    }
    *(u16x8*)&Acat[(size_t)r * 512 + 256 + c8] = o;
}

// ---------------- row L2 normalize + fused column-sum ------------------
__global__ __launch_bounds__(512)
void l2norm_kernel(float* __restrict__ out, float* __restrict__ gsum) {
    __shared__ float sm[8 * 256];
    int wave = threadIdx.x >> 6;   // 0..7
    int lane = threadIdx.x & 63;
    float c0 = 0.f, c1 = 0.f, c2 = 0.f, c3 = 0.f;
    for (int r = blockIdx.x * 8 + wave; r < NN; r += gridDim.x * 8) {
        float4 v = *(float4*)&out[(size_t)r * 256 + lane * 4];
        float sq = v.x * v.x + v.y * v.y + v.z * v.z + v.w * v.w;
#pragma unroll
        for (int o = 32; o; o >>= 1) sq += __shfl_xor(sq, o);
        float invn = 1.0f / fmaxf(sqrtf(sq), 1e-12f);
        v.x *= invn; v.y *= invn; v.z *= invn; v.w *= invn;
        *(float4*)&out[(size_t)r * 256 + lane * 4] = v;
        c0 += v.x; c1 += v.y; c2 += v.z; c3 += v.w;
    }
    *(float4*)&sm[wave * 256 + lane * 4] = make_float4(c0, c1, c2, c3);
    __syncthreads();
    int t = threadIdx.x;
    if (t < 256) {
        float s = 0.f;
#pragma unroll
        for (int w = 0; w < 8; w++) s += sm[w * 256 + t];
        atomicAdd(&gsum[t], s);
    }
}

__global__ void graph_kernel(const float* __restrict__ gsum, float* __restrict__ gout) {
    __shared__ float wsum[4];
    int j = threadIdx.x;
    float v = gsum[j] * (1.0f / (float)NN);
    float sq = v * v;
#pragma unroll
    for (int o = 32; o; o >>= 1) sq += __shfl_xor(sq, o);
    if ((j & 63) == 0) wsum[j >> 6] = sq;
    __syncthreads();
    float tot = wsum[0] + wsum[1] + wsum[2] + wsum[3];
    gout[j] = v / fmaxf(sqrtf(tot), 1e-12f);
}

extern "C" void kernel_launch(void* const* d_in, const int* in_sizes, int n_in,
                              void* d_out, int out_size, void* d_ws, size_t ws_size,
                              hipStream_t stream) {
    const float* x      = (const float*)d_in[0];
    const float* W1_l   = (const float*)d_in[1];
    const float* b1_l   = (const float*)d_in[2];
    const float* W1_r   = (const float*)d_in[3];
    const float* W2_l   = (const float*)d_in[4];
    const float* b2_l   = (const float*)d_in[5];
    const float* W2_r   = (const float*)d_in[6];
    const float* gamma1 = (const float*)d_in[7];
    const float* beta1  = (const float*)d_in[8];
    const int*   eidx   = (const int*)d_in[9];
    const int* src = eidx;
    const int* dst = eidx + NE;

    char* wsb = (char*)d_ws;
    int*   deg   = (int*)(wsb + 0);
    int*   offs  = (int*)(wsb + 200000);
    int*   cur   = (int*)(wsb + 400004);
    int*   csr   = (int*)(wsb + 600004);
    int*   part  = (int*)(wsb + 3800064);
    int*   base  = (int*)(wsb + 3801088);
    float* stats = (float*)(wsb + 3802112);
    float* gsum  = (float*)(wsb + 3804160);
    float* scale = (float*)(wsb + 3805184);
    float* shift = (float*)(wsb + 3806208);
    u16*   Wcat1 = (u16*)(wsb + 3807232);
    u16*   Wcat2 = (u16*)(wsb + 4069376);
    u16*   hb    = (u16*)(wsb + 4331520);
    u16*   Acat  = (u16*)(wsb + 29931520);
    float* out   = (float*)d_out;
    float* gout  = out + (size_t)NN * 256;

    hipMemsetAsync(deg, 0, NN * sizeof(int), stream);
    hipMemsetAsync(stats, 0, 3072, stream);  // stats + gsum

    wconv_kernel<<<256, 256, 0, stream>>>(W1_l, W1_r, W2_l, W2_r, Wcat1, Wcat2);
    xconv_kernel<<<12500, 256, 0, stream>>>(x, Acat);

    degree_kernel<<<(NE + 255) / 256, 256, 0, stream>>>(dst, deg);
    scanA_kernel<<<SCB, 256, 0, stream>>>(deg, part);
    scanB_kernel<<<1, 256, 0, stream>>>(part, base, offs);
    scanC_kernel<<<SCB, 256, 0, stream>>>(deg, base, offs, cur);
    fill_kernel<<<(NE + 255) / 256, 256, 0, stream>>>(src, dst, cur, csr);

    dim3 ggrid((NN + 127) / 128, 2);

    // layer 1
    agg_kernel<<<12500, 256, 0, stream>>>(Acat, csr, offs, Acat);
    mfma_gemm_kernel<1><<<ggrid, 256, 0, stream>>>(Acat, Wcat1, b1_l, hb);
    colstats_kernel<<<512, 256, 0, stream>>>(hb, stats);
    bnfin_kernel<<<1, 256, 0, stream>>>(stats, gamma1, beta1, scale, shift);
    bnrelu_kernel<<<6250, 256, 0, stream>>>(hb, scale, shift, Acat);

    // layer 2
    agg_kernel<<<12500, 256, 0, stream>>>(Acat, csr, offs, Acat);
    mfma_gemm_kernel<0><<<ggrid, 256, 0, stream>>>(Acat, Wcat2, b2_l, out);

    // outputs
    l2norm_kernel<<<1024, 512, 0, stream>>>(out, gsum);
    graph_kernel<<<1, 256, 0, stream>>>(gsum, gout);
}

// Round 8
// 395.409 us; speedup vs baseline: 4.8470x; 1.0161x over previous
//
#include <hip/hip_runtime.h>
#include <math.h>

#define NN 50000
#define NE 800000
#define D  256
#define SCB 196  // ceil(NN/256)

typedef unsigned short u16;
typedef __attribute__((ext_vector_type(8))) short short8;
typedef __attribute__((ext_vector_type(8))) unsigned short u16x8;
typedef __attribute__((ext_vector_type(4))) float f32x4;

// f32 -> bf16 round-to-nearest-even
__device__ __forceinline__ u16 f2b(float f) {
    unsigned u = __float_as_uint(f);
    return (u16)((u + 0x7FFFu + ((u >> 16) & 1u)) >> 16);
}
__device__ __forceinline__ float b2f(u16 b) {
    return __uint_as_float(((unsigned)b) << 16);
}

// async global->LDS, 16 bytes per lane; LDS dest = wave-uniform base + lane*16
__device__ __forceinline__ void gl16(const u16* g, u16* l) {
    __builtin_amdgcn_global_load_lds(
        (const __attribute__((address_space(1))) void*)g,
        (__attribute__((address_space(3))) void*)l, 16, 0, 0);
}

// ---------------- CSR build ----------------
__global__ void degree_kernel(const int* __restrict__ dst, int* __restrict__ deg) {
    int e = blockIdx.x * blockDim.x + threadIdx.x;
    if (e < NE) atomicAdd(&deg[dst[e]], 1);
}

__global__ void scanA_kernel(const int* __restrict__ deg, int* __restrict__ partial) {
    int t = threadIdx.x;
    int i = blockIdx.x * 256 + t;
    int v = (i < NN) ? deg[i] : 0;
#pragma unroll
    for (int o = 32; o; o >>= 1) v += __shfl_xor(v, o);
    __shared__ int sm[4];
    if ((t & 63) == 0) sm[t >> 6] = v;
    __syncthreads();
    if (t == 0) partial[blockIdx.x] = sm[0] + sm[1] + sm[2] + sm[3];
}

__global__ void scanB_kernel(const int* __restrict__ partial, int* __restrict__ base,
                             int* __restrict__ offs) {
    __shared__ int sm[256];
    int t = threadIdx.x;
    int v = (t < SCB) ? partial[t] : 0;
    sm[t] = v;
    __syncthreads();
    for (int off = 1; off < 256; off <<= 1) {
        int u = 0;
        if (t >= off) u = sm[t - off];
        __syncthreads();
        sm[t] += u;
        __syncthreads();
    }
    if (t < SCB) base[t] = sm[t] - v;
    if (t == 255) offs[NN] = sm[255];
}

__global__ void scanC_kernel(const int* __restrict__ deg, const int* __restrict__ base,
                             int* __restrict__ offs, int* __restrict__ cur) {
    __shared__ int sm[256];
    int t = threadIdx.x;
    int i = blockIdx.x * 256 + t;
    int v = (i < NN) ? deg[i] : 0;
    sm[t] = v;
    __syncthreads();
    for (int off = 1; off < 256; off <<= 1) {
        int u = 0;
        if (t >= off) u = sm[t - off];
        __syncthreads();
        sm[t] += u;
        __syncthreads();
    }
    int o = base[blockIdx.x] + sm[t] - v;
    if (i < NN) {
        offs[i] = o;
        cur[i] = o;
    }
}

__global__ void fill_kernel(const int* __restrict__ src, const int* __restrict__ dst,
                            int* __restrict__ cur, int* __restrict__ csr) {
    int e = blockIdx.x * blockDim.x + threadIdx.x;
    if (e < NE) {
        int pos = atomicAdd(&cur[dst[e]], 1);
        csr[pos] = src[e];
    }
}

// ---------------- weight pack ----------------
__global__ void wconv_kernel(const float* __restrict__ W1l, const float* __restrict__ W1r,
                             const float* __restrict__ W2l, const float* __restrict__ W2r,
                             u16* __restrict__ Wcat1, u16* __restrict__ Wcat2) {
    int r = blockIdx.x;
    int j = threadIdx.x;
    Wcat1[r * 512 + j]       = f2b(W1l[r * 256 + j]);
    Wcat1[r * 512 + 256 + j] = f2b(W1r[r * 256 + j]);
    Wcat2[r * 512 + j]       = f2b(W2l[r * 256 + j]);
    Wcat2[r * 512 + 256 + j] = f2b(W2r[r * 256 + j]);
}

// ---------------- x (f32) -> Acat right half (bf16) ----------------
__global__ void xconv_kernel(const float* __restrict__ x, u16* __restrict__ Acat) {
    int idx = blockIdx.x * blockDim.x + threadIdx.x;
    int r = idx >> 6;
    int c4 = (idx & 63) * 4;
    float4 v = *(const float4*)&x[(size_t)r * 256 + c4];
    ushort4 o;
    o.x = f2b(v.x); o.y = f2b(v.y); o.z = f2b(v.z); o.w = f2b(v.w);
    *(ushort4*)&Acat[(size_t)r * 512 + 256 + c4] = o;
}

// ---------------- mean aggregation: one wave per node --------------------
__global__ __launch_bounds__(256)
void agg_kernel(const u16* __restrict__ Acat, const int* __restrict__ csr,
                const int* __restrict__ offs, u16* __restrict__ AcatW) {
    int wid = (blockIdx.x * blockDim.x + threadIdx.x) >> 6;
    int lane = threadIdx.x & 63;
    if (wid >= NN) return;
    int beg = offs[wid];
    int end = offs[wid + 1];
    int deg = end - beg;
    int half = lane >> 5;
    int lc = (lane & 31) * 8;
    int mid = beg + ((deg + 1) >> 1);
    int e  = half ? mid : beg;
    int hi = half ? end : mid;
    float a[8] = {0.f, 0.f, 0.f, 0.f, 0.f, 0.f, 0.f, 0.f};
    for (; e + 3 < hi; e += 4) {
        int s0 = csr[e + 0];
        int s1 = csr[e + 1];
        int s2 = csr[e + 2];
        int s3 = csr[e + 3];
        u16x8 v0 = *(const u16x8*)&Acat[(size_t)s0 * 512 + 256 + lc];
        u16x8 v1 = *(const u16x8*)&Acat[(size_t)s1 * 512 + 256 + lc];
        u16x8 v2 = *(const u16x8*)&Acat[(size_t)s2 * 512 + 256 + lc];
        u16x8 v3 = *(const u16x8*)&Acat[(size_t)s3 * 512 + 256 + lc];
#pragma unroll
        for (int i = 0; i < 8; i++)
            a[i] += (b2f(v0[i]) + b2f(v1[i])) + (b2f(v2[i]) + b2f(v3[i]));
    }
    for (; e < hi; e++) {
        int s0 = csr[e];
        u16x8 v0 = *(const u16x8*)&Acat[(size_t)s0 * 512 + 256 + lc];
#pragma unroll
        for (int i = 0; i < 8; i++) a[i] += b2f(v0[i]);
    }
#pragma unroll
    for (int i = 0; i < 8; i++) a[i] += __shfl_xor(a[i], 32);
    float sc = (deg > 0) ? 1.0f / (float)deg : 0.0f;
    if (half == 0) {
        u16x8 o;
#pragma unroll
        for (int i = 0; i < 8; i++) o[i] = f2b(a[i] * sc);
        *(u16x8*)&AcatW[(size_t)wid * 512 + lc] = o;
    }
}

// ---------------- MFMA GEMM: C[NN][256] = A[NN][512] @ W[256][512]^T + bias
// 4-buffer LDS ring, stage tile t+2 at iter t, counted s_waitcnt vmcnt(8)
// + raw s_barrier: prefetches stay in flight across barriers (never drain 0).
// Buffer staged at iter t was last read at iter t-2 -> two barriers separate
// read and overwrite (safe).
template<int BF16_OUT>
__global__ __launch_bounds__(256)
void mfma_gemm_kernel(const u16* __restrict__ A, const u16* __restrict__ W,
                      const float* __restrict__ bias, void* __restrict__ Cout) {
    __shared__ u16 As[4][128 * 32];
    __shared__ u16 Bs[4][128 * 32];
    const int tid = threadIdx.x;
    const int l = tid & 63;
    const int wid = tid >> 6;
    const int wr = wid >> 1, wc = wid & 1;
    const int row0 = blockIdx.x * 128;
    const int col0 = blockIdx.y * 128;

    const u16* aptr[2];
    const u16* bptr[2];
#pragma unroll
    for (int i = 0; i < 2; i++) {
        int row = wid * 32 + i * 16 + (l >> 2);
        int kg = (l & 3) ^ ((row >> 1) & 3);   // pre-swizzled k-group (source side)
        int ra = row0 + row;
        if (ra > NN - 1) ra = NN - 1;
        aptr[i] = A + (size_t)ra * 512 + kg * 8;
        bptr[i] = W + (size_t)(col0 + row) * 512 + kg * 8;
    }

    f32x4 acc[4][4] = {};

#define STAGE(b, t)                                                          \
    do {                                                                     \
        _Pragma("unroll") for (int i_ = 0; i_ < 2; i_++) {                   \
            u16* al = &As[b][(wid * 32 + i_ * 16) * 32];                     \
            u16* bl = &Bs[b][(wid * 32 + i_ * 16) * 32];                     \
            gl16(aptr[i_] + (t) * 32, al);                                   \
            gl16(bptr[i_] + (t) * 32, bl);                                   \
        }                                                                    \
    } while (0)

    STAGE(0, 0);
    STAGE(1, 1);

    const int kq = l >> 4;
    const int sw = ((l & 15) >> 1) & 3;
#pragma unroll
    for (int t = 0; t < 16; t++) {
        if (t + 2 < 16) STAGE((t + 2) & 3, t + 2);

        // wait until own loads for tile t are complete; keep 2 stages in flight
        if (t < 14)       asm volatile("s_waitcnt vmcnt(8)" ::: "memory");
        else if (t == 14) asm volatile("s_waitcnt vmcnt(4)" ::: "memory");
        else              asm volatile("s_waitcnt vmcnt(0)" ::: "memory");
        __builtin_amdgcn_s_barrier();      // all waves' tile-t stages landed
        __builtin_amdgcn_sched_barrier(0); // pin: no reads hoisted above

        short8 af[4], bf[4];
#pragma unroll
        for (int m = 0; m < 4; m++) {
            int row = wr * 64 + m * 16 + (l & 15);
            af[m] = *(const short8*)&As[t & 3][row * 32 + (kq ^ sw) * 8];
        }
#pragma unroll
        for (int n = 0; n < 4; n++) {
            int row = wc * 64 + n * 16 + (l & 15);
            bf[n] = *(const short8*)&Bs[t & 3][row * 32 + (kq ^ sw) * 8];
        }
#pragma unroll
        for (int m = 0; m < 4; m++)
#pragma unroll
            for (int n = 0; n < 4; n++)
                acc[m][n] = __builtin_amdgcn_mfma_f32_16x16x32_bf16(
                    af[m], bf[n], acc[m][n], 0, 0, 0);
    }
#undef STAGE

    const int cq = l >> 4;
    const int cc = l & 15;
#pragma unroll
    for (int m = 0; m < 4; m++) {
#pragma unroll
        for (int n = 0; n < 4; n++) {
#pragma unroll
            for (int j = 0; j < 4; j++) {
                int r = row0 + wr * 64 + m * 16 + cq * 4 + j;
                int c = col0 + wc * 64 + n * 16 + cc;
                if (r < NN) {
                    float v = acc[m][n][j] + bias[c];
                    if (BF16_OUT)
                        ((u16*)Cout)[(size_t)r * 256 + c] = f2b(v);
                    else
                        ((float*)Cout)[(size_t)r * 256 + c] = v;
                }
            }
        }
    }
}

// ---------------- per-column sum & sumsq for BN (bf16 input) ----------------
__global__ void colstats_kernel(const u16* __restrict__ h, float* __restrict__ stats) {
    int j = threadIdx.x;
    float s0 = 0.f, s1 = 0.f;
    for (int r = blockIdx.x; r < NN; r += gridDim.x) {
        float v = b2f(h[(size_t)r * 256 + j]);
        s0 += v;
        s1 += v * v;
    }
    atomicAdd(&stats[j], s0);
    atomicAdd(&stats[256 + j], s1);
}

__global__ void bnfin_kernel(const float* __restrict__ stats,
                             const float* __restrict__ gamma,
                             const float* __restrict__ beta,
                             float* __restrict__ scale,
                             float* __restrict__ shift) {
    int j = threadIdx.x;
    const float invN = 1.0f / (float)NN;
    float mu = stats[j] * invN;
    float var = stats[256 + j] * invN - mu * mu;
    float sc = gamma[j] * rsqrtf(var + 1e-5f);
    scale[j] = sc;
    shift[j] = beta[j] - mu * sc;
}

// ---------------- BN + ReLU ----------------
__global__ void bnrelu_kernel(const u16* __restrict__ hb,
                              const float* __restrict__ scale,
                              const float* __restrict__ shift,
                              u16* __restrict__ Acat) {
    int idx = blockIdx.x * blockDim.x + threadIdx.x;
    int r = idx >> 5;
    int c8 = (idx & 31) * 8;
    u16x8 v = *(const u16x8*)&hb[(size_t)r * 256 + c8];
    u16x8 o;
#pragma unroll
    for (int i = 0; i < 8; i++) {
        float f = b2f(v[i]) * scale[c8 + i] + shift[c8 + i];
        o[i] = f2b(fmaxf(f, 0.f));
    }
    *(u16x8*)&Acat[(size_t)r * 512 + 256 + c8] = o;
}

// ---------------- row L2 normalize + fused column-sum ------------------
__global__ __launch_bounds__(512)
void l2norm_kernel(float* __restrict__ out, float* __restrict__ gsum) {
    __shared__ float sm[8 * 256];
    int wave = threadIdx.x >> 6;   // 0..7
    int lane = threadIdx.x & 63;
    float c0 = 0.f, c1 = 0.f, c2 = 0.f, c3 = 0.f;
    for (int r = blockIdx.x * 8 + wave; r < NN; r += gridDim.x * 8) {
        float4 v = *(float4*)&out[(size_t)r * 256 + lane * 4];
        float sq = v.x * v.x + v.y * v.y + v.z * v.z + v.w * v.w;
#pragma unroll
        for (int o = 32; o; o >>= 1) sq += __shfl_xor(sq, o);
        float invn = 1.0f / fmaxf(sqrtf(sq), 1e-12f);
        v.x *= invn; v.y *= invn; v.z *= invn; v.w *= invn;
        *(float4*)&out[(size_t)r * 256 + lane * 4] = v;
        c0 += v.x; c1 += v.y; c2 += v.z; c3 += v.w;
    }
    *(float4*)&sm[wave * 256 + lane * 4] = make_float4(c0, c1, c2, c3);
    __syncthreads();
    int t = threadIdx.x;
    if (t < 256) {
        float s = 0.f;
#pragma unroll
        for (int w = 0; w < 8; w++) s += sm[w * 256 + t];
        atomicAdd(&gsum[t], s);
    }
}

__global__ void graph_kernel(const float* __restrict__ gsum, float* __restrict__ gout) {
    __shared__ float wsum[4];
    int j = threadIdx.x;
    float v = gsum[j] * (1.0f / (float)NN);
    float sq = v * v;
#pragma unroll
    for (int o = 32; o; o >>= 1) sq += __shfl_xor(sq, o);
    if ((j & 63) == 0) wsum[j >> 6] = sq;
    __syncthreads();
    float tot = wsum[0] + wsum[1] + wsum[2] + wsum[3];
    gout[j] = v / fmaxf(sqrtf(tot), 1e-12f);
}

extern "C" void kernel_launch(void* const* d_in, const int* in_sizes, int n_in,
                              void* d_out, int out_size, void* d_ws, size_t ws_size,
                              hipStream_t stream) {
    const float* x      = (const float*)d_in[0];
    const float* W1_l   = (const float*)d_in[1];
    const float* b1_l   = (const float*)d_in[2];
    const float* W1_r   = (const float*)d_in[3];
    const float* W2_l   = (const float*)d_in[4];
    const float* b2_l   = (const float*)d_in[5];
    const float* W2_r   = (const float*)d_in[6];
    const float* gamma1 = (const float*)d_in[7];
    const float* beta1  = (const float*)d_in[8];
    const int*   eidx   = (const int*)d_in[9];
    const int* src = eidx;
    const int* dst = eidx + NE;

    char* wsb = (char*)d_ws;
    int*   deg   = (int*)(wsb + 0);
    int*   offs  = (int*)(wsb + 200000);
    int*   cur   = (int*)(wsb + 400004);
    int*   csr   = (int*)(wsb + 600004);
    int*   part  = (int*)(wsb + 3800064);
    int*   base  = (int*)(wsb + 3801088);
    float* stats = (float*)(wsb + 3802112);
    float* gsum  = (float*)(wsb + 3804160);
    float* scale = (float*)(wsb + 3805184);
    float* shift = (float*)(wsb + 3806208);
    u16*   Wcat1 = (u16*)(wsb + 3807232);
    u16*   Wcat2 = (u16*)(wsb + 4069376);
    u16*   hb    = (u16*)(wsb + 4331520);
    u16*   Acat  = (u16*)(wsb + 29931520);
    float* out   = (float*)d_out;
    float* gout  = out + (size_t)NN * 256;

    hipMemsetAsync(deg, 0, NN * sizeof(int), stream);
    hipMemsetAsync(stats, 0, 3072, stream);  // stats + gsum

    wconv_kernel<<<256, 256, 0, stream>>>(W1_l, W1_r, W2_l, W2_r, Wcat1, Wcat2);
    xconv_kernel<<<12500, 256, 0, stream>>>(x, Acat);

    degree_kernel<<<(NE + 255) / 256, 256, 0, stream>>>(dst, deg);
    scanA_kernel<<<SCB, 256, 0, stream>>>(deg, part);
    scanB_kernel<<<1, 256, 0, stream>>>(part, base, offs);
    scanC_kernel<<<SCB, 256, 0, stream>>>(deg, base, offs, cur);
    fill_kernel<<<(NE + 255) / 256, 256, 0, stream>>>(src, dst, cur, csr);

    dim3 ggrid((NN + 127) / 128, 2);

    // layer 1
    agg_kernel<<<12500, 256, 0, stream>>>(Acat, csr, offs, Acat);
    mfma_gemm_kernel<1><<<ggrid, 256, 0, stream>>>(Acat, Wcat1, b1_l, hb);
    colstats_kernel<<<512, 256, 0, stream>>>(hb, stats);
    bnfin_kernel<<<1, 256, 0, stream>>>(stats, gamma1, beta1, scale, shift);
    bnrelu_kernel<<<6250, 256, 0, stream>>>(hb, scale, shift, Acat);

    // layer 2
    agg_kernel<<<12500, 256, 0, stream>>>(Acat, csr, offs, Acat);
    mfma_gemm_kernel<0><<<ggrid, 256, 0, stream>>>(Acat, Wcat2, b2_l, out);

    // outputs
    l2norm_kernel<<<1024, 512, 0, stream>>>(out, gsum);
    graph_kernel<<<1, 256, 0, stream>>>(gsum, gout);
}

// Round 9
// 376.941 us; speedup vs baseline: 5.0845x; 1.0490x over previous
//
#include <hip/hip_runtime.h>
#include <math.h>

#define NN 50000
#define NE 800000
#define D  256
#define SCB 196  // ceil(NN/256)

typedef unsigned short u16;
typedef __attribute__((ext_vector_type(8))) short short8;
typedef __attribute__((ext_vector_type(8))) unsigned short u16x8;
typedef __attribute__((ext_vector_type(4))) float f32x4;

// f32 -> bf16 round-to-nearest-even
__device__ __forceinline__ u16 f2b(float f) {
    unsigned u = __float_as_uint(f);
    return (u16)((u + 0x7FFFu + ((u >> 16) & 1u)) >> 16);
}
__device__ __forceinline__ float b2f(u16 b) {
    return __uint_as_float(((unsigned)b) << 16);
}

// async global->LDS, 16 bytes per lane; LDS dest = wave-uniform base + lane*16
__device__ __forceinline__ void gl16(const u16* g, u16* l) {
    __builtin_amdgcn_global_load_lds(
        (const __attribute__((address_space(1))) void*)g,
        (__attribute__((address_space(3))) void*)l, 16, 0, 0);
}

// ---------------- CSR build ----------------
// 4 edges per thread: 4 independent atomics in flight (latency hiding)
__global__ void degree_kernel(const int* __restrict__ dst, int* __restrict__ deg) {
    int e0 = (blockIdx.x * blockDim.x + threadIdx.x) * 4;
    if (e0 + 3 < NE) {
        int4 d = *(const int4*)&dst[e0];
        atomicAdd(&deg[d.x], 1);
        atomicAdd(&deg[d.y], 1);
        atomicAdd(&deg[d.z], 1);
        atomicAdd(&deg[d.w], 1);
    } else {
        for (int e = e0; e < NE; e++) atomicAdd(&deg[dst[e]], 1);
    }
}

__global__ void scanA_kernel(const int* __restrict__ deg, int* __restrict__ partial) {
    int t = threadIdx.x;
    int i = blockIdx.x * 256 + t;
    int v = (i < NN) ? deg[i] : 0;
#pragma unroll
    for (int o = 32; o; o >>= 1) v += __shfl_xor(v, o);
    __shared__ int sm[4];
    if ((t & 63) == 0) sm[t >> 6] = v;
    __syncthreads();
    if (t == 0) partial[blockIdx.x] = sm[0] + sm[1] + sm[2] + sm[3];
}

__global__ void scanB_kernel(const int* __restrict__ partial, int* __restrict__ base,
                             int* __restrict__ offs) {
    __shared__ int sm[256];
    int t = threadIdx.x;
    int v = (t < SCB) ? partial[t] : 0;
    sm[t] = v;
    __syncthreads();
    for (int off = 1; off < 256; off <<= 1) {
        int u = 0;
        if (t >= off) u = sm[t - off];
        __syncthreads();
        sm[t] += u;
        __syncthreads();
    }
    if (t < SCB) base[t] = sm[t] - v;
    if (t == 255) offs[NN] = sm[255];
}

__global__ void scanC_kernel(const int* __restrict__ deg, const int* __restrict__ base,
                             int* __restrict__ offs, int* __restrict__ cur) {
    __shared__ int sm[256];
    int t = threadIdx.x;
    int i = blockIdx.x * 256 + t;
    int v = (i < NN) ? deg[i] : 0;
    sm[t] = v;
    __syncthreads();
    for (int off = 1; off < 256; off <<= 1) {
        int u = 0;
        if (t >= off) u = sm[t - off];
        __syncthreads();
        sm[t] += u;
        __syncthreads();
    }
    int o = base[blockIdx.x] + sm[t] - v;
    if (i < NN) {
        offs[i] = o;
        cur[i] = o;
    }
}

// 4 edges per thread: int4 loads, 4 independent atomic+store chains
__global__ void fill_kernel(const int* __restrict__ src, const int* __restrict__ dst,
                            int* __restrict__ cur, int* __restrict__ csr) {
    int e0 = (blockIdx.x * blockDim.x + threadIdx.x) * 4;
    if (e0 + 3 < NE) {
        int4 d = *(const int4*)&dst[e0];
        int4 s = *(const int4*)&src[e0];
        int p0 = atomicAdd(&cur[d.x], 1);
        int p1 = atomicAdd(&cur[d.y], 1);
        int p2 = atomicAdd(&cur[d.z], 1);
        int p3 = atomicAdd(&cur[d.w], 1);
        csr[p0] = s.x;
        csr[p1] = s.y;
        csr[p2] = s.z;
        csr[p3] = s.w;
    } else {
        for (int e = e0; e < NE; e++) {
            int pos = atomicAdd(&cur[dst[e]], 1);
            csr[pos] = src[e];
        }
    }
}

// ---------------- weight pack ----------------
__global__ void wconv_kernel(const float* __restrict__ W1l, const float* __restrict__ W1r,
                             const float* __restrict__ W2l, const float* __restrict__ W2r,
                             u16* __restrict__ Wcat1, u16* __restrict__ Wcat2) {
    int r = blockIdx.x;
    int j = threadIdx.x;
    Wcat1[r * 512 + j]       = f2b(W1l[r * 256 + j]);
    Wcat1[r * 512 + 256 + j] = f2b(W1r[r * 256 + j]);
    Wcat2[r * 512 + j]       = f2b(W2l[r * 256 + j]);
    Wcat2[r * 512 + 256 + j] = f2b(W2r[r * 256 + j]);
}

// ---------------- x (f32) -> Acat right half (bf16) ----------------
__global__ void xconv_kernel(const float* __restrict__ x, u16* __restrict__ Acat) {
    int idx = blockIdx.x * blockDim.x + threadIdx.x;
    int r = idx >> 6;
    int c4 = (idx & 63) * 4;
    float4 v = *(const float4*)&x[(size_t)r * 256 + c4];
    ushort4 o;
    o.x = f2b(v.x); o.y = f2b(v.y); o.z = f2b(v.z); o.w = f2b(v.w);
    *(ushort4*)&Acat[(size_t)r * 512 + 256 + c4] = o;
}

// ---------------- mean aggregation: one wave per node, 8 gathers in flight --
__global__ __launch_bounds__(256)
void agg_kernel(const u16* __restrict__ Acat, const int* __restrict__ csr,
                const int* __restrict__ offs, u16* __restrict__ AcatW) {
    int wid = (blockIdx.x * blockDim.x + threadIdx.x) >> 6;
    int lane = threadIdx.x & 63;
    if (wid >= NN) return;
    int beg = offs[wid];
    int end = offs[wid + 1];
    int deg = end - beg;
    int half = lane >> 5;
    int lc = (lane & 31) * 8;
    int mid = beg + ((deg + 1) >> 1);
    int e  = half ? mid : beg;
    int hi = half ? end : mid;
    float a[8] = {0.f, 0.f, 0.f, 0.f, 0.f, 0.f, 0.f, 0.f};
    for (; e + 7 < hi; e += 8) {
        int s0 = csr[e + 0], s1 = csr[e + 1], s2 = csr[e + 2], s3 = csr[e + 3];
        int s4 = csr[e + 4], s5 = csr[e + 5], s6 = csr[e + 6], s7 = csr[e + 7];
        u16x8 v0 = *(const u16x8*)&Acat[(size_t)s0 * 512 + 256 + lc];
        u16x8 v1 = *(const u16x8*)&Acat[(size_t)s1 * 512 + 256 + lc];
        u16x8 v2 = *(const u16x8*)&Acat[(size_t)s2 * 512 + 256 + lc];
        u16x8 v3 = *(const u16x8*)&Acat[(size_t)s3 * 512 + 256 + lc];
        u16x8 v4 = *(const u16x8*)&Acat[(size_t)s4 * 512 + 256 + lc];
        u16x8 v5 = *(const u16x8*)&Acat[(size_t)s5 * 512 + 256 + lc];
        u16x8 v6 = *(const u16x8*)&Acat[(size_t)s6 * 512 + 256 + lc];
        u16x8 v7 = *(const u16x8*)&Acat[(size_t)s7 * 512 + 256 + lc];
#pragma unroll
        for (int i = 0; i < 8; i++)
            a[i] += ((b2f(v0[i]) + b2f(v1[i])) + (b2f(v2[i]) + b2f(v3[i]))) +
                    ((b2f(v4[i]) + b2f(v5[i])) + (b2f(v6[i]) + b2f(v7[i])));
    }
    for (; e + 3 < hi; e += 4) {
        int s0 = csr[e + 0], s1 = csr[e + 1], s2 = csr[e + 2], s3 = csr[e + 3];
        u16x8 v0 = *(const u16x8*)&Acat[(size_t)s0 * 512 + 256 + lc];
        u16x8 v1 = *(const u16x8*)&Acat[(size_t)s1 * 512 + 256 + lc];
        u16x8 v2 = *(const u16x8*)&Acat[(size_t)s2 * 512 + 256 + lc];
        u16x8 v3 = *(const u16x8*)&Acat[(size_t)s3 * 512 + 256 + lc];
#pragma unroll
        for (int i = 0; i < 8; i++)
            a[i] += (b2f(v0[i]) + b2f(v1[i])) + (b2f(v2[i]) + b2f(v3[i]));
    }
    for (; e < hi; e++) {
        int s0 = csr[e];
        u16x8 v0 = *(const u16x8*)&Acat[(size_t)s0 * 512 + 256 + lc];
#pragma unroll
        for (int i = 0; i < 8; i++) a[i] += b2f(v0[i]);
    }
#pragma unroll
    for (int i = 0; i < 8; i++) a[i] += __shfl_xor(a[i], 32);
    float sc = (deg > 0) ? 1.0f / (float)deg : 0.0f;
    if (half == 0) {
        u16x8 o;
#pragma unroll
        for (int i = 0; i < 8; i++) o[i] = f2b(a[i] * sc);
        *(u16x8*)&AcatW[(size_t)wid * 512 + lc] = o;
    }
}

// ---------------- MFMA GEMM: C[NN][256] = A[NN][512] @ W[256][512]^T + bias
// 4-buffer LDS ring, counted vmcnt, raw barrier (R8 pipeline).
// STATS=1: fused per-column sum/sumsq of C into stats[] (replaces colstats).
template<int BF16_OUT, int STATS>
__global__ __launch_bounds__(256)
void mfma_gemm_kernel(const u16* __restrict__ A, const u16* __restrict__ W,
                      const float* __restrict__ bias, void* __restrict__ Cout,
                      float* __restrict__ stats) {
    __shared__ u16 As[4][128 * 32];
    __shared__ u16 Bs[4][128 * 32];
    const int tid = threadIdx.x;
    const int l = tid & 63;
    const int wid = tid >> 6;
    const int wr = wid >> 1, wc = wid & 1;
    const int row0 = blockIdx.x * 128;
    const int col0 = blockIdx.y * 128;

    const u16* aptr[2];
    const u16* bptr[2];
#pragma unroll
    for (int i = 0; i < 2; i++) {
        int row = wid * 32 + i * 16 + (l >> 2);
        int kg = (l & 3) ^ ((row >> 1) & 3);   // pre-swizzled k-group (source side)
        int ra = row0 + row;
        if (ra > NN - 1) ra = NN - 1;
        aptr[i] = A + (size_t)ra * 512 + kg * 8;
        bptr[i] = W + (size_t)(col0 + row) * 512 + kg * 8;
    }

    f32x4 acc[4][4] = {};

#define STAGE(b, t)                                                          \
    do {                                                                     \
        _Pragma("unroll") for (int i_ = 0; i_ < 2; i_++) {                   \
            u16* al = &As[b][(wid * 32 + i_ * 16) * 32];                     \
            u16* bl = &Bs[b][(wid * 32 + i_ * 16) * 32];                     \
            gl16(aptr[i_] + (t) * 32, al);                                   \
            gl16(bptr[i_] + (t) * 32, bl);                                   \
        }                                                                    \
    } while (0)

    STAGE(0, 0);
    STAGE(1, 1);

    const int kq = l >> 4;
    const int sw = ((l & 15) >> 1) & 3;
#pragma unroll
    for (int t = 0; t < 16; t++) {
        if (t + 2 < 16) STAGE((t + 2) & 3, t + 2);

        if (t < 14)       asm volatile("s_waitcnt vmcnt(8)" ::: "memory");
        else if (t == 14) asm volatile("s_waitcnt vmcnt(4)" ::: "memory");
        else              asm volatile("s_waitcnt vmcnt(0)" ::: "memory");
        __builtin_amdgcn_s_barrier();
        __builtin_amdgcn_sched_barrier(0);

        short8 af[4], bf[4];
#pragma unroll
        for (int m = 0; m < 4; m++) {
            int row = wr * 64 + m * 16 + (l & 15);
            af[m] = *(const short8*)&As[t & 3][row * 32 + (kq ^ sw) * 8];
        }
#pragma unroll
        for (int n = 0; n < 4; n++) {
            int row = wc * 64 + n * 16 + (l & 15);
            bf[n] = *(const short8*)&Bs[t & 3][row * 32 + (kq ^ sw) * 8];
        }
#pragma unroll
        for (int m = 0; m < 4; m++)
#pragma unroll
            for (int n = 0; n < 4; n++)
                acc[m][n] = __builtin_amdgcn_mfma_f32_16x16x32_bf16(
                    af[m], bf[n], acc[m][n], 0, 0, 0);
    }
#undef STAGE

    // epilogue: C/D layout col = lane&15, row = (lane>>4)*4 + j
    const int cq = l >> 4;
    const int cc = l & 15;
#pragma unroll
    for (int n = 0; n < 4; n++) {
        int c = col0 + wc * 64 + n * 16 + cc;
        float t0 = 0.f, t1 = 0.f;
#pragma unroll
        for (int m = 0; m < 4; m++) {
#pragma unroll
            for (int j = 0; j < 4; j++) {
                int r = row0 + wr * 64 + m * 16 + cq * 4 + j;
                if (r < NN) {
                    float v = acc[m][n][j] + bias[c];
                    if (BF16_OUT)
                        ((u16*)Cout)[(size_t)r * 256 + c] = f2b(v);
                    else
                        ((float*)Cout)[(size_t)r * 256 + c] = v;
                    if (STATS) { t0 += v; t1 += v * v; }
                }
            }
        }
        if (STATS) {
            // reduce over cq (4 row-quads of this wave share column c)
            t0 += __shfl_xor(t0, 16); t1 += __shfl_xor(t1, 16);
            t0 += __shfl_xor(t0, 32); t1 += __shfl_xor(t1, 32);
            if (cq == 0) {
                atomicAdd(&stats[c], t0);
                atomicAdd(&stats[256 + c], t1);
            }
        }
    }
}

__global__ void bnfin_kernel(const float* __restrict__ stats,
                             const float* __restrict__ gamma,
                             const float* __restrict__ beta,
                             float* __restrict__ scale,
                             float* __restrict__ shift) {
    int j = threadIdx.x;
    const float invN = 1.0f / (float)NN;
    float mu = stats[j] * invN;
    float var = stats[256 + j] * invN - mu * mu;
    float sc = gamma[j] * rsqrtf(var + 1e-5f);
    scale[j] = sc;
    shift[j] = beta[j] - mu * sc;
}

// ---------------- BN + ReLU ----------------
__global__ void bnrelu_kernel(const u16* __restrict__ hb,
                              const float* __restrict__ scale,
                              const float* __restrict__ shift,
                              u16* __restrict__ Acat) {
    int idx = blockIdx.x * blockDim.x + threadIdx.x;
    int r = idx >> 5;
    int c8 = (idx & 31) * 8;
    u16x8 v = *(const u16x8*)&hb[(size_t)r * 256 + c8];
    u16x8 o;
#pragma unroll
    for (int i = 0; i < 8; i++) {
        float f = b2f(v[i]) * scale[c8 + i] + shift[c8 + i];
        o[i] = f2b(fmaxf(f, 0.f));
    }
    *(u16x8*)&Acat[(size_t)r * 512 + 256 + c8] = o;
}

// ---------------- row L2 normalize + fused column-sum ------------------
__global__ __launch_bounds__(512)
void l2norm_kernel(float* __restrict__ out, float* __restrict__ gsum) {
    __shared__ float sm[8 * 256];
    int wave = threadIdx.x >> 6;   // 0..7
    int lane = threadIdx.x & 63;
    float c0 = 0.f, c1 = 0.f, c2 = 0.f, c3 = 0.f;
    for (int r = blockIdx.x * 8 + wave; r < NN; r += gridDim.x * 8) {
        float4 v = *(float4*)&out[(size_t)r * 256 + lane * 4];
        float sq = v.x * v.x + v.y * v.y + v.z * v.z + v.w * v.w;
#pragma unroll
        for (int o = 32; o; o >>= 1) sq += __shfl_xor(sq, o);
        float invn = 1.0f / fmaxf(sqrtf(sq), 1e-12f);
        v.x *= invn; v.y *= invn; v.z *= invn; v.w *= invn;
        *(float4*)&out[(size_t)r * 256 + lane * 4] = v;
        c0 += v.x; c1 += v.y; c2 += v.z; c3 += v.w;
    }
    *(float4*)&sm[wave * 256 + lane * 4] = make_float4(c0, c1, c2, c3);
    __syncthreads();
    int t = threadIdx.x;
    if (t < 256) {
        float s = 0.f;
#pragma unroll
        for (int w = 0; w < 8; w++) s += sm[w * 256 + t];
        atomicAdd(&gsum[t], s);
    }
}

__global__ void graph_kernel(const float* __restrict__ gsum, float* __restrict__ gout) {
    __shared__ float wsum[4];
    int j = threadIdx.x;
    float v = gsum[j] * (1.0f / (float)NN);
    float sq = v * v;
#pragma unroll
    for (int o = 32; o; o >>= 1) sq += __shfl_xor(sq, o);
    if ((j & 63) == 0) wsum[j >> 6] = sq;
    __syncthreads();
    float tot = wsum[0] + wsum[1] + wsum[2] + wsum[3];
    gout[j] = v / fmaxf(sqrtf(tot), 1e-12f);
}

extern "C" void kernel_launch(void* const* d_in, const int* in_sizes, int n_in,
                              void* d_out, int out_size, void* d_ws, size_t ws_size,
                              hipStream_t stream) {
    const float* x      = (const float*)d_in[0];
    const float* W1_l   = (const float*)d_in[1];
    const float* b1_l   = (const float*)d_in[2];
    const float* W1_r   = (const float*)d_in[3];
    const float* W2_l   = (const float*)d_in[4];
    const float* b2_l   = (const float*)d_in[5];
    const float* W2_r   = (const float*)d_in[6];
    const float* gamma1 = (const float*)d_in[7];
    const float* beta1  = (const float*)d_in[8];
    const int*   eidx   = (const int*)d_in[9];
    const int* src = eidx;
    const int* dst = eidx + NE;

    char* wsb = (char*)d_ws;
    int*   deg   = (int*)(wsb + 0);
    int*   offs  = (int*)(wsb + 200000);
    int*   cur   = (int*)(wsb + 400004);
    int*   csr   = (int*)(wsb + 600004);
    int*   part  = (int*)(wsb + 3800064);
    int*   base  = (int*)(wsb + 3801088);
    float* stats = (float*)(wsb + 3802112);
    float* gsum  = (float*)(wsb + 3804160);
    float* scale = (float*)(wsb + 3805184);
    float* shift = (float*)(wsb + 3806208);
    u16*   Wcat1 = (u16*)(wsb + 3807232);
    u16*   Wcat2 = (u16*)(wsb + 4069376);
    u16*   hb    = (u16*)(wsb + 4331520);
    u16*   Acat  = (u16*)(wsb + 29931520);
    float* out   = (float*)d_out;
    float* gout  = out + (size_t)NN * 256;

    hipMemsetAsync(deg, 0, NN * sizeof(int), stream);
    hipMemsetAsync(stats, 0, 3072, stream);  // stats + gsum

    wconv_kernel<<<256, 256, 0, stream>>>(W1_l, W1_r, W2_l, W2_r, Wcat1, Wcat2);
    xconv_kernel<<<12500, 256, 0, stream>>>(x, Acat);

    degree_kernel<<<(NE / 4 + 255) / 256, 256, 0, stream>>>(dst, deg);
    scanA_kernel<<<SCB, 256, 0, stream>>>(deg, part);
    scanB_kernel<<<1, 256, 0, stream>>>(part, base, offs);
    scanC_kernel<<<SCB, 256, 0, stream>>>(deg, base, offs, cur);
    fill_kernel<<<(NE / 4 + 255) / 256, 256, 0, stream>>>(src, dst, cur, csr);

    dim3 ggrid((NN + 127) / 128, 2);

    // layer 1 (stats fused into GEMM epilogue)
    agg_kernel<<<12500, 256, 0, stream>>>(Acat, csr, offs, Acat);
    mfma_gemm_kernel<1, 1><<<ggrid, 256, 0, stream>>>(Acat, Wcat1, b1_l, hb, stats);
    bnfin_kernel<<<1, 256, 0, stream>>>(stats, gamma1, beta1, scale, shift);
    bnrelu_kernel<<<6250, 256, 0, stream>>>(hb, scale, shift, Acat);

    // layer 2
    agg_kernel<<<12500, 256, 0, stream>>>(Acat, csr, offs, Acat);
    mfma_gemm_kernel<0, 0><<<ggrid, 256, 0, stream>>>(Acat, Wcat2, b2_l, out, stats);

    // outputs
    l2norm_kernel<<<1024, 512, 0, stream>>>(out, gsum);
    graph_kernel<<<1, 256, 0, stream>>>(gsum, gout);
}